// Round 3
// baseline (342.617 us; speedup 1.0000x reference)
//
#include <hip/hip_runtime.h>
#include <math.h>

#define Bn 64
#define Sn 512
#define Hn 768
#define ATT_H 100
#define CLS_H 300
#define Mtok (Bn*Sn)          // 32768
#define NP 112                // padded ATT_H (7 x 16)
#define NT 7                  // col tiles of 16

#define W1T_N (NP*Hn)         // 86016 (fragment-ordered bf16)
#define W3T_N (CLS_H*Hn)      // 230400
#define POOL_N (Bn*Hn)        // 49152

typedef __attribute__((ext_vector_type(8))) short short8;
typedef __attribute__((ext_vector_type(4))) float floatx4;

__device__ inline float sigf(float x) { return 1.0f / (1.0f + expf(-x)); }

__device__ inline unsigned short f2bf(float x) {
    union { float f; unsigned int u; } v; v.f = x;
    unsigned int r = (v.u + 0x7FFFu + ((v.u >> 16) & 1u)) >> 16;
    return (unsigned short)r;
}

__device__ inline float wred_sum(float v) {
    #pragma unroll
    for (int d = 32; d; d >>= 1) v += __shfl_down(v, d, 64);
    return v;
}
__device__ inline float wred_max(float v) {
    #pragma unroll
    for (int d = 32; d; d >>= 1) v = fmaxf(v, __shfl_down(v, d, 64));
    return v;
}
__device__ inline float wred_min(float v) {
    #pragma unroll
    for (int d = 32; d; d >>= 1) v = fminf(v, __shfl_down(v, d, 64));
    return v;
}

// ---------------------------------------------------------------------------
// K0: prep.
// w1t FRAGMENT-ORDERED bf16: w1t[((kstep*7 + ct)*64 + lane)*8 + e]
//   = W1[k][n], n = ct*16 + (lane&15), k = kstep*32 + (lane>>4)*8 + e,
//   zero-padded for n >= ATT_H.
// w3t[j][k] = W3[k][j]; b1w2[n] = (b1[n], W2[n]); zero pooled and zpart.
// ---------------------------------------------------------------------------
__global__ __launch_bounds__(256) void k0_prep(
    const float* __restrict__ W1, const float* __restrict__ b1,
    const float* __restrict__ W2, const float* __restrict__ W3,
    unsigned short* __restrict__ w1t, float* __restrict__ b1w2,
    float* __restrict__ w3t, float* __restrict__ pooled,
    float* __restrict__ zpart)
{
    int idx = blockIdx.x * 256 + threadIdx.x;
    if (idx < W1T_N) {
        int e = idx & 7;
        int lane = (idx >> 3) & 63;
        int t = idx >> 9;                 // kstep*7 + ct
        int ct = t % 7, kstep = t / 7;
        int n = ct * 16 + (lane & 15);
        int k = kstep * 32 + (lane >> 4) * 8 + e;
        float v = (n < ATT_H) ? W1[(size_t)k * ATT_H + n] : 0.f;
        w1t[idx] = f2bf(v);
    } else if (idx < W1T_N + W3T_N) {
        int i = idx - W1T_N;
        int j = i / Hn, k = i - j * Hn;
        w3t[i] = W3[(size_t)k * CLS_H + j];
    } else if (idx < W1T_N + W3T_N + NP) {
        int j = idx - (W1T_N + W3T_N);
        b1w2[2 * j]     = (j < ATT_H) ? b1[j] : 0.f;
        b1w2[2 * j + 1] = (j < ATT_H) ? W2[j] : 0.f;
    } else if (idx < W1T_N + W3T_N + NP + POOL_N) {
        pooled[idx - (W1T_N + W3T_N + NP)] = 0.f;
    } else if (idx < W1T_N + W3T_N + NP + POOL_N + 5 * Bn) {
        zpart[idx - (W1T_N + W3T_N + NP + POOL_N)] = 0.f;
    }
}

// ---------------------------------------------------------------------------
// K1 (v4): software-pipelined, k-split x4, B-reuse x2, swizzled LDS.
// R2 post-mortem: VGPR=56 -> compiler serialized load->pack->LDS->b-load->
// mfma per chunk; 1.7 TB/s latency-bound. Fixes:
//  * block = 32 tokens (2 M-tiles), 4 waves = 4 k-quarters (192 cols each).
//    Grid 1024 = exactly 4 blocks/CU (no tail round), 16 waves/CU.
//  * per chunk: 8 coalesced float4 loads/lane; schedule = pack(ch) ->
//    PREFETCH(ch+1) -> compute(ch): next chunk's 8 loads are in flight
//    under the whole MFMA phase. Pipeline depth 3.
//  * wave-private LDS, row stride 128 B, XOR swizzle byte^=(row&7)<<4:
//    conflict-free ds_write_b64 and ds_read_b128 (floor occupancy of all
//    32 banks). No barriers in the main loop.
//  * B fragments loaded per-ct (compiler-scheduled depth), each reused for
//    both M-tiles.
// End-of-kernel: 4-way k-combine per M-tile through LDS + epilogue.
// ---------------------------------------------------------------------------
__global__ __launch_bounds__(256, 4) void k1_att(
    const float* __restrict__ h, const unsigned short* __restrict__ w1t,
    const float* __restrict__ b1w2, const float* __restrict__ b2,
    float* __restrict__ out_hidden, float* __restrict__ att)
{
    // 4 waves x double-buffer x (32 rows x 128 B) = 32768 B
    __shared__ __align__(16) char smem[4 * 2 * 32 * 128];

    const int tid = threadIdx.x;
    const int wave = tid >> 6, lane = tid & 63;
    const int u = lane & 15, q = lane >> 4;
    const int g = wave;                    // k-quarter 0..3
    const int tok0 = blockIdx.x * 32;

    const int lr = lane >> 4;              // staging row-within-quad 0..3
    const int lcb = (lane & 15) * 8;       // staging byte col within row (bf16)

    floatx4 acc[2][NT];
    #pragma unroll
    for (int mt = 0; mt < 2; mt++)
        #pragma unroll
        for (int ct = 0; ct < NT; ct++) acc[mt][ct] = (floatx4)0.f;

    const short8* __restrict__ w1f = (const short8*)w1t;
    char* const sbase = smem + wave * (2 * 32 * 128);

    floatx4 v[8];
    // prologue: chunk 0 loads
    #pragma unroll
    for (int j = 0; j < 8; j++) {
        size_t gidx = (size_t)(tok0 + j * 4 + lr) * Hn + g * 192 + lcb / 2;
        v[j] = *(const floatx4*)(h + gidx);
    }

    #pragma unroll
    for (int ch = 0; ch < 3; ch++) {
        char* stage = sbase + (ch & 1) * (32 * 128);
        const int kbase = g * 192 + ch * 64;

        // pack chunk ch: passthrough store + bf16 -> swizzled LDS
        #pragma unroll
        for (int j = 0; j < 8; j++) {
            int row = j * 4 + lr;
            size_t gidx = (size_t)(tok0 + row) * Hn + kbase + lcb / 2;
            *(floatx4*)(out_hidden + gidx) = v[j];
            ushort4 bv;
            bv.x = f2bf(v[j].x); bv.y = f2bf(v[j].y);
            bv.z = f2bf(v[j].z); bv.w = f2bf(v[j].w);
            *(ushort4*)(stage + row * 128 + (lcb ^ ((row & 7) << 4))) = bv;
        }

        // prefetch chunk ch+1 (in flight during compute below)
        if (ch < 2) {
            #pragma unroll
            for (int j = 0; j < 8; j++) {
                size_t gidx = (size_t)(tok0 + j * 4 + lr) * Hn + kbase + 64 + lcb / 2;
                v[j] = *(const floatx4*)(h + gidx);
            }
        }

        // compute chunk ch from wave-private LDS
        #pragma unroll
        for (int ks = 0; ks < 2; ks++) {
            const int kstep = g * 6 + ch * 2 + ks;
            short8 a0 = *(const short8*)(stage + (u) * 128
                                         + ((ks * 64 + q * 16) ^ ((u & 7) << 4)));
            short8 a1 = *(const short8*)(stage + (16 + u) * 128
                                         + ((ks * 64 + q * 16) ^ ((u & 7) << 4)));
            #pragma unroll
            for (int ct = 0; ct < NT; ct++) {
                short8 bfr = w1f[(kstep * 7 + ct) * 64 + lane];
                acc[0][ct] = __builtin_amdgcn_mfma_f32_16x16x32_bf16(a0, bfr, acc[0][ct], 0, 0, 0);
                acc[1][ct] = __builtin_amdgcn_mfma_f32_16x16x32_bf16(a1, bfr, acc[1][ct], 0, 0, 0);
            }
        }
    }

    // 4-way k-combine per M-tile, then epilogue on wave 0.
    float* cb = (float*)smem;     // 3*64*28*4 = 21504 B <= 32768 B
    #pragma unroll
    for (int mt = 0; mt < 2; mt++) {
        __syncthreads();
        if (g > 0) {
            #pragma unroll
            for (int ct = 0; ct < NT; ct++)
                *(floatx4*)(&cb[((g - 1) * 64 + lane) * 28 + ct * 4]) = acc[mt][ct];
        }
        __syncthreads();
        if (g == 0) {
            #pragma unroll
            for (int o = 0; o < 3; o++)
                #pragma unroll
                for (int ct = 0; ct < NT; ct++)
                    acc[mt][ct] += *(const floatx4*)(&cb[(o * 64 + lane) * 28 + ct * 4]);
            // z[token] = sum_n tanh(D[token][n] + b1[n]) * W2[n]
            float z[4] = {0.f, 0.f, 0.f, 0.f};
            #pragma unroll
            for (int ct = 0; ct < NT; ct++) {
                float2 bw = *(const float2*)(b1w2 + (ct * 16 + u) * 2);
                #pragma unroll
                for (int r = 0; r < 4; r++)
                    z[r] += tanhf(acc[mt][ct][r] + bw.x) * bw.y;
            }
            #pragma unroll
            for (int mask = 1; mask < 16; mask <<= 1) {
                #pragma unroll
                for (int r = 0; r < 4; r++) z[r] += __shfl_xor(z[r], mask, 64);
            }
            if (u == 0) {
                float bb2 = b2[0];
                #pragma unroll
                for (int r = 0; r < 4; r++)
                    att[tok0 + mt * 16 + q * 4 + r] = sigf(z[r] + bb2);
            }
        }
    }
}

// ---------------------------------------------------------------------------
// K2: per batch row — word max via direct forward chase; one pass, one
// barrier. Reductions unchanged. (verified R1/R2)
// ---------------------------------------------------------------------------
__global__ __launch_bounds__(256) void k2_seg(
    const float* __restrict__ att, const int* __restrict__ offset,
    const float* __restrict__ labels, float* __restrict__ masked_out,
    float* __restrict__ sum_m, float* __restrict__ slab_o,
    float* __restrict__ tl_o, float* __restrict__ mino_o,
    float* __restrict__ maxm_o)
{
    const int b = blockIdx.x, tid = threadIdx.x;
    __shared__ float attl[Sn];
    __shared__ int   startl[Sn];
    __shared__ float rsum[4], rtl[4], rsl[4], rmn[4], rmx[4];

    for (int s = tid; s < Sn; s += 256) {
        attl[s] = att[b * Sn + s];
        startl[s] = (offset[(size_t)(b * Sn + s) * 2] == 0) ? 1 : 0;
    }
    __syncthreads();

    float lsum = 0.f, ltl = 0.f, lslab = -1e30f, lmin = 1e30f, lmax = -1e30f;
    for (int s = tid; s < Sn; s += 256) {
        float lab = labels[b * Sn + s];
        int st = startl[s];
        float m = 0.f;
        if (st && lab != -1.0f) {
            m = attl[s];
            for (int t = s + 1; t < Sn && !startl[t]; t++)
                m = fmaxf(m, attl[t]);
        }
        masked_out[b * Sn + s] = m;
        lsum += m;
        float zl = (lab == 1.0f) ? 1.f : 0.f;
        ltl += (m - zl) * (m - zl);
        lslab = fmaxf(lslab, lab);
        float om = (m == 0.f) ? 1.f : m;
        lmin = fminf(lmin, om);
        lmax = fmaxf(lmax, m);
    }
    int wid = tid >> 6, lane = tid & 63;
    lsum = wred_sum(lsum); ltl = wred_sum(ltl);
    lslab = wred_max(lslab); lmin = wred_min(lmin); lmax = wred_max(lmax);
    if (lane == 0) { rsum[wid]=lsum; rtl[wid]=ltl; rsl[wid]=lslab; rmn[wid]=lmin; rmx[wid]=lmax; }
    __syncthreads();
    if (tid == 0) {
        sum_m[b]  = rsum[0]+rsum[1]+rsum[2]+rsum[3];
        tl_o[b]   = rtl[0]+rtl[1]+rtl[2]+rtl[3];
        slab_o[b] = fmaxf(fmaxf(rsl[0],rsl[1]), fmaxf(rsl[2],rsl[3]));
        mino_o[b] = fminf(fminf(rmn[0],rmn[1]), fminf(rmn[2],rmn[3]));
        maxm_o[b] = fmaxf(fmaxf(rmx[0],rmx[1]), fmaxf(rmx[2],rmx[3]));
    }
}

// ---------------------------------------------------------------------------
// K3: pooled[b,:] += sum_s h[b,s,:] * masked[b,s]/sum_m[b] over a 16-row
// s-chunk. grid (64 b, 32 sc) x 192 threads, fully coalesced.
// fp32 atomicAdd partials (32-way per address, pipelined through L2).
// ---------------------------------------------------------------------------
__global__ __launch_bounds__(192) void k3_pool(
    const float* __restrict__ h, const float* __restrict__ masked,
    const float* __restrict__ sum_m, float* __restrict__ pooled)
{
    const int b = blockIdx.x, sc = blockIdx.y;
    const int tid = threadIdx.x;
    __shared__ float nrm[16];
    if (tid < 16)
        nrm[tid] = masked[b * Sn + sc * 16 + tid] * (1.0f / sum_m[b]);
    __syncthreads();
    const floatx4* hp = (const floatx4*)(h + ((size_t)b * Sn + sc * 16) * Hn) + tid;
    float ax = 0.f, ay = 0.f, az = 0.f, aw = 0.f;
    #pragma unroll 8
    for (int s = 0; s < 16; s++) {
        floatx4 v = hp[(size_t)s * (Hn / 4)];
        float w = nrm[s];
        ax += v.x * w; ay += v.y * w; az += v.z * w; aw += v.w * w;
    }
    float* pp = pooled + (size_t)b * Hn + tid * 4;
    atomicAdd(pp + 0, ax); atomicAdd(pp + 1, ay);
    atomicAdd(pp + 2, az); atomicAdd(pp + 3, aw);
}

// ---------------------------------------------------------------------------
// K4: zpart[jc,b] = sum_{j in chunk} tanh(pooled[b]·W3T[j] + b3[j]) * W4[j].
// grid (64 b, 5 jc) x 256 threads; 4 threads per j, float4 dot over k.
// ---------------------------------------------------------------------------
__global__ __launch_bounds__(256) void k4_sent(
    const float* __restrict__ pooled, const float* __restrict__ w3t,
    const float* __restrict__ b3, const float* __restrict__ W4,
    float* __restrict__ zpart)
{
    const int b = blockIdx.x, jc = blockIdx.y;
    const int tid = threadIdx.x;
    __shared__ __align__(16) float pl[Hn];
    __shared__ float yred[64];
    for (int k = tid; k < Hn; k += 256) pl[k] = pooled[(size_t)b * Hn + k];
    if (tid < 64) yred[tid] = 0.f;
    __syncthreads();
    int jj = tid >> 2, ks = tid & 3;
    float a = 0.f;
    if (jj < 60) {
        int j = jc * 60 + jj;
        const floatx4* wr = (const floatx4*)(w3t + (size_t)j * Hn) + ks * 48;
        const floatx4* pr = (const floatx4*)pl + ks * 48;
        #pragma unroll 8
        for (int i = 0; i < 48; i++) {
            floatx4 wv = wr[i]; floatx4 pv = pr[i];
            a += wv.x * pv.x + wv.y * pv.y + wv.z * pv.z + wv.w * pv.w;
        }
    }
    a += __shfl_xor(a, 1, 64);
    a += __shfl_xor(a, 2, 64);
    if (jj < 60 && ks == 0) {
        int j = jc * 60 + jj;
        yred[jj] = tanhf(a + b3[j]) * W4[j];
    }
    __syncthreads();
    if (tid < 64) {
        float y = yred[tid];
        y = wred_sum(y);
        if (tid == 0) zpart[jc * Bn + b] = y;
    }
}

// ---------------------------------------------------------------------------
// K5: sent + final scalars. One wave; b = lane.
// ---------------------------------------------------------------------------
__global__ __launch_bounds__(64) void k5_loss(
    const float* __restrict__ zpart, const float* __restrict__ b4,
    const float* __restrict__ slab, const float* __restrict__ tl,
    const float* __restrict__ mino, const float* __restrict__ maxm,
    float* __restrict__ out, float* __restrict__ out_sent)
{
    int t = threadIdx.x;
    float z = b4[0];
    #pragma unroll
    for (int jc = 0; jc < 5; jc++) z += zpart[jc * Bn + t];
    float sent = sigf(z);
    out_sent[t] = sent;
    float sl = slab[t];
    float e1 = (sent - sl) * (sent - sl);
    float e2 = tl[t];
    float e3 = mino[t] * mino[t];
    float mm = maxm[t] - sl;
    float e4 = mm * mm;
    e1 = wred_sum(e1); e2 = wred_sum(e2); e3 = wred_sum(e3); e4 = wred_sum(e4);
    if (t == 0) {
        out[1] = e1;
        out[2] = e2;
        out[3] = e3;
        out[4] = e4;
        out[0] = e1 + e2 + 0.01f * (e3 + e4);
    }
}

extern "C" void kernel_launch(void* const* d_in, const int* in_sizes, int n_in,
                              void* d_out, int out_size, void* d_ws, size_t ws_size,
                              hipStream_t stream) {
    (void)in_sizes; (void)n_in; (void)out_size; (void)ws_size;
    const float* h      = (const float*)d_in[0];
    const int*   offset = (const int*)d_in[1];
    const float* labels = (const float*)d_in[2];
    const float* W1     = (const float*)d_in[3];
    const float* b1     = (const float*)d_in[4];
    const float* W2     = (const float*)d_in[5];
    const float* b2     = (const float*)d_in[6];
    const float* W3     = (const float*)d_in[7];
    const float* b3     = (const float*)d_in[8];
    const float* W4     = (const float*)d_in[9];
    const float* b4     = (const float*)d_in[10];

    float* out        = (float*)d_out;
    float* out_hidden = out + 5;
    float* out_masked = out_hidden + (size_t)Bn * Sn * Hn;   // 25,165,824
    float* out_sent   = out_masked + (size_t)Bn * Sn;        // 32,768

    float* ws      = (float*)d_ws;
    float* att     = ws;                        // 32768
    float* sum_m   = att + Mtok;                // 64
    float* slab    = sum_m + Bn;
    float* tlb     = slab + Bn;
    float* mino    = tlb + Bn;
    float* maxm    = mino + Bn;
    float* pooled  = maxm + Bn;                 // 49152
    float* zpart   = pooled + POOL_N;           // 320
    float* b1w2    = zpart + 5 * Bn;            // 224
    float* w3t     = b1w2 + 2 * NP;             // 230400
    unsigned short* w1t = (unsigned short*)(w3t + W3T_N);  // 86016 bf16

    int k0_total = W1T_N + W3T_N + NP + POOL_N + 5 * Bn;
    k0_prep<<<(k0_total + 255) / 256, 256, 0, stream>>>(W1, b1, W2, W3,
                                                        w1t, b1w2, w3t, pooled, zpart);
    k1_att<<<Mtok / 32, 256, 0, stream>>>(h, w1t, b1w2, b2, out_hidden, att);
    k2_seg<<<Bn, 256, 0, stream>>>(att, offset, labels, out_masked,
                                   sum_m, slab, tlb, mino, maxm);
    k3_pool<<<dim3(Bn, 32), 192, 0, stream>>>(h, out_masked, sum_m, pooled);
    k4_sent<<<dim3(Bn, 5), 256, 0, stream>>>(pooled, w3t, b3, W4, zpart);
    k5_loss<<<1, 64, 0, stream>>>(zpart, b4, slab, tlb, mino, maxm, out, out_sent);
}

// Round 4
// 338.349 us; speedup vs baseline: 1.0126x; 1.0126x over previous
//
#include <hip/hip_runtime.h>
#include <math.h>

#define Bn 64
#define Sn 512
#define Hn 768
#define ATT_H 100
#define CLS_H 300
#define Mtok (Bn*Sn)          // 32768
#define NP 112                // padded ATT_H (7 x 16)
#define NT 7                  // col tiles of 16

#define W1T_N (NP*Hn)         // 86016 (fragment-ordered bf16)
#define W3T_N (CLS_H*Hn)      // 230400
#define POOL_N (Bn*Hn)        // 49152

typedef __attribute__((ext_vector_type(8))) short short8;
typedef __attribute__((ext_vector_type(4))) float floatx4;

__device__ inline float sigf(float x) { return 1.0f / (1.0f + expf(-x)); }

__device__ inline unsigned short f2bf(float x) {
    union { float f; unsigned int u; } v; v.f = x;
    unsigned int r = (v.u + 0x7FFFu + ((v.u >> 16) & 1u)) >> 16;
    return (unsigned short)r;
}

__device__ inline float wred_sum(float v) {
    #pragma unroll
    for (int d = 32; d; d >>= 1) v += __shfl_down(v, d, 64);
    return v;
}
__device__ inline float wred_max(float v) {
    #pragma unroll
    for (int d = 32; d; d >>= 1) v = fmaxf(v, __shfl_down(v, d, 64));
    return v;
}
__device__ inline float wred_min(float v) {
    #pragma unroll
    for (int d = 32; d; d >>= 1) v = fminf(v, __shfl_down(v, d, 64));
    return v;
}

// ---------------------------------------------------------------------------
// K0: prep.
// w1t FRAGMENT-ORDERED bf16: w1t[((kstep*7 + ct)*64 + lane)*8 + e]
//   = W1[k][n], n = ct*16 + (lane&15), k = kstep*32 + (lane>>4)*8 + e,
//   zero-padded for n >= ATT_H.
// w3t[j][k] = W3[k][j]; b1w2[n] = (b1[n], W2[n]); zero pooled and zpart.
// ---------------------------------------------------------------------------
__global__ __launch_bounds__(256) void k0_prep(
    const float* __restrict__ W1, const float* __restrict__ b1,
    const float* __restrict__ W2, const float* __restrict__ W3,
    unsigned short* __restrict__ w1t, float* __restrict__ b1w2,
    float* __restrict__ w3t, float* __restrict__ pooled,
    float* __restrict__ zpart)
{
    int idx = blockIdx.x * 256 + threadIdx.x;
    if (idx < W1T_N) {
        int e = idx & 7;
        int lane = (idx >> 3) & 63;
        int t = idx >> 9;                 // kstep*7 + ct
        int ct = t % 7, kstep = t / 7;
        int n = ct * 16 + (lane & 15);
        int k = kstep * 32 + (lane >> 4) * 8 + e;
        float v = (n < ATT_H) ? W1[(size_t)k * ATT_H + n] : 0.f;
        w1t[idx] = f2bf(v);
    } else if (idx < W1T_N + W3T_N) {
        int i = idx - W1T_N;
        int j = i / Hn, k = i - j * Hn;
        w3t[i] = W3[(size_t)k * CLS_H + j];
    } else if (idx < W1T_N + W3T_N + NP) {
        int j = idx - (W1T_N + W3T_N);
        b1w2[2 * j]     = (j < ATT_H) ? b1[j] : 0.f;
        b1w2[2 * j + 1] = (j < ATT_H) ? W2[j] : 0.f;
    } else if (idx < W1T_N + W3T_N + NP + POOL_N) {
        pooled[idx - (W1T_N + W3T_N + NP)] = 0.f;
    } else if (idx < W1T_N + W3T_N + NP + POOL_N + 5 * Bn) {
        zpart[idx - (W1T_N + W3T_N + NP + POOL_N)] = 0.f;
    }
}

// ---------------------------------------------------------------------------
// K1 (v5): B-reuse x4 to cut vector-port traffic; no-spill register budget.
// R3 post-mortem: VGPR capped at 64 -> scratch spills (+92 MB phantom HBM
// traffic, SGPR=112). R2 analysis: total vector-port bytes = A-load 100 +
// A-store 100 + B-frag reloads 344 MB = 553 MB at the ~9.5 B/cyc/CU port
// ceiling -> 95 us. Fix = traffic reduction, not latency tricks:
//  * block = 64 tokens (4 M-tiles), 4 waves = 4 k-quarters (192 cols each).
//    Grid 512 = 2 blocks/CU exact, 2 waves/SIMD.
//  * each wave computes 4 M-tiles with the SAME B fragment held in a reg
//    (reuse x4): B traffic 344 -> 88 MB. Total ~288 MB -> ~50 us predicted.
//  * chunk = 32 k-cols: 8 coalesced float4 loads/lane (8 rows x 128 B per
//    instruction). Schedule: pack(ch) -> prefetch(ch+1) -> compute(ch);
//    only v[8] (32 regs) double-buffered in registers.
//  * acc[4][7] = 112 regs; total ~195 under __launch_bounds__(256,2)
//    (256-reg budget) -> no spill.
//  * wave-private LDS 4 KB x dbuf, row stride 64 B, XOR swizzle
//    byte ^= (row&3)<<4 (same verified-conflict-free family as R3).
//    No barriers in the main loop.
// End: 4-way k-combine per M-tile (fully unrolled -> no runtime acc index).
// ---------------------------------------------------------------------------
__global__ __launch_bounds__(256, 2) void k1_att(
    const float* __restrict__ h, const unsigned short* __restrict__ w1t,
    const float* __restrict__ b1w2, const float* __restrict__ b2,
    float* __restrict__ out_hidden, float* __restrict__ att)
{
    // 4 waves x dbuf x (64 rows x 64 B) = 32768 B; reused as combine buffer.
    __shared__ __align__(16) char smem[32768];

    const int tid = threadIdx.x;
    const int wave = tid >> 6, lane = tid & 63;
    const int u = lane & 15, q = lane >> 4;
    const int g = wave;                    // k-quarter 0..3
    const int tok0 = blockIdx.x * 64;

    const int lrow = lane >> 3;            // 0..7
    const int lcol = (lane & 7) * 4;       // float col within 32-col chunk

    floatx4 acc[4][NT];
    #pragma unroll
    for (int m = 0; m < 4; m++)
        #pragma unroll
        for (int ct = 0; ct < NT; ct++) acc[m][ct] = (floatx4)0.f;

    const short8* __restrict__ w1f = (const short8*)w1t;
    char* const sb = smem + wave * 8192;

    floatx4 v[8];
    // prologue: chunk 0 loads
    #pragma unroll
    for (int j = 0; j < 8; j++) {
        size_t gidx = (size_t)(tok0 + j * 8 + lrow) * Hn + g * 192 + lcol;
        v[j] = *(const floatx4*)(h + gidx);
    }

    #pragma unroll
    for (int ch = 0; ch < 6; ch++) {
        char* stage = sb + (ch & 1) * 4096;
        const int kbase = g * 192 + ch * 32;

        // pack chunk ch: passthrough store + bf16 -> swizzled wave-private LDS
        #pragma unroll
        for (int j = 0; j < 8; j++) {
            int row = j * 8 + lrow;
            size_t gidx = (size_t)(tok0 + row) * Hn + kbase + lcol;
            *(floatx4*)(out_hidden + gidx) = v[j];
            ushort4 bv;
            bv.x = f2bf(v[j].x); bv.y = f2bf(v[j].y);
            bv.z = f2bf(v[j].z); bv.w = f2bf(v[j].w);
            *(ushort4*)(stage + row * 64 + ((lcol * 2) ^ ((row & 3) << 4))) = bv;
        }

        // prefetch chunk ch+1 (in flight during compute below)
        if (ch < 5) {
            #pragma unroll
            for (int j = 0; j < 8; j++) {
                size_t gidx = (size_t)(tok0 + j * 8 + lrow) * Hn + kbase + 32 + lcol;
                v[j] = *(const floatx4*)(h + gidx);
            }
        }

        // compute chunk ch: one k-step, 4 M-tiles per B fragment
        const int kstep = g * 6 + ch;
        short8 a[4];
        #pragma unroll
        for (int m = 0; m < 4; m++)
            a[m] = *(const short8*)(stage + (m * 16 + u) * 64
                                    + ((q * 16) ^ ((u & 3) << 4)));
        #pragma unroll
        for (int ct = 0; ct < NT; ct++) {
            short8 bfr = w1f[(kstep * 7 + ct) * 64 + lane];
            #pragma unroll
            for (int m = 0; m < 4; m++)
                acc[m][ct] = __builtin_amdgcn_mfma_f32_16x16x32_bf16(a[m], bfr, acc[m][ct], 0, 0, 0);
        }
    }

    // 4-way k-combine per M-tile + epilogue (wave 0). Fully unrolled so all
    // acc indices are compile-time (runtime-indexed ext_vector -> scratch).
    float* cb = (float*)smem;     // 3*64*28 floats = 21504 B <= 32768 B
    #pragma unroll
    for (int mt = 0; mt < 4; mt++) {
        __syncthreads();
        if (g > 0) {
            #pragma unroll
            for (int ct = 0; ct < NT; ct++)
                *(floatx4*)(&cb[((g - 1) * 64 + lane) * 28 + ct * 4]) = acc[mt][ct];
        }
        __syncthreads();
        if (g == 0) {
            #pragma unroll
            for (int o = 0; o < 3; o++)
                #pragma unroll
                for (int ct = 0; ct < NT; ct++)
                    acc[mt][ct] += *(const floatx4*)(&cb[(o * 64 + lane) * 28 + ct * 4]);
            // z[token] = sum_n tanh(D[token][n] + b1[n]) * W2[n]
            float z[4] = {0.f, 0.f, 0.f, 0.f};
            #pragma unroll
            for (int ct = 0; ct < NT; ct++) {
                float2 bw = *(const float2*)(b1w2 + (ct * 16 + u) * 2);
                #pragma unroll
                for (int r = 0; r < 4; r++)
                    z[r] += tanhf(acc[mt][ct][r] + bw.x) * bw.y;
            }
            #pragma unroll
            for (int mask = 1; mask < 16; mask <<= 1) {
                #pragma unroll
                for (int r = 0; r < 4; r++) z[r] += __shfl_xor(z[r], mask, 64);
            }
            if (u == 0) {
                float bb2 = b2[0];
                #pragma unroll
                for (int r = 0; r < 4; r++)
                    att[tok0 + mt * 16 + q * 4 + r] = sigf(z[r] + bb2);
            }
        }
    }
}

// ---------------------------------------------------------------------------
// K2: per batch row — word max via direct forward chase; one pass, one
// barrier. Reductions unchanged. (verified R1-R3)
// ---------------------------------------------------------------------------
__global__ __launch_bounds__(256) void k2_seg(
    const float* __restrict__ att, const int* __restrict__ offset,
    const float* __restrict__ labels, float* __restrict__ masked_out,
    float* __restrict__ sum_m, float* __restrict__ slab_o,
    float* __restrict__ tl_o, float* __restrict__ mino_o,
    float* __restrict__ maxm_o)
{
    const int b = blockIdx.x, tid = threadIdx.x;
    __shared__ float attl[Sn];
    __shared__ int   startl[Sn];
    __shared__ float rsum[4], rtl[4], rsl[4], rmn[4], rmx[4];

    for (int s = tid; s < Sn; s += 256) {
        attl[s] = att[b * Sn + s];
        startl[s] = (offset[(size_t)(b * Sn + s) * 2] == 0) ? 1 : 0;
    }
    __syncthreads();

    float lsum = 0.f, ltl = 0.f, lslab = -1e30f, lmin = 1e30f, lmax = -1e30f;
    for (int s = tid; s < Sn; s += 256) {
        float lab = labels[b * Sn + s];
        int st = startl[s];
        float m = 0.f;
        if (st && lab != -1.0f) {
            m = attl[s];
            for (int t = s + 1; t < Sn && !startl[t]; t++)
                m = fmaxf(m, attl[t]);
        }
        masked_out[b * Sn + s] = m;
        lsum += m;
        float zl = (lab == 1.0f) ? 1.f : 0.f;
        ltl += (m - zl) * (m - zl);
        lslab = fmaxf(lslab, lab);
        float om = (m == 0.f) ? 1.f : m;
        lmin = fminf(lmin, om);
        lmax = fmaxf(lmax, m);
    }
    int wid = tid >> 6, lane = tid & 63;
    lsum = wred_sum(lsum); ltl = wred_sum(ltl);
    lslab = wred_max(lslab); lmin = wred_min(lmin); lmax = wred_max(lmax);
    if (lane == 0) { rsum[wid]=lsum; rtl[wid]=ltl; rsl[wid]=lslab; rmn[wid]=lmin; rmx[wid]=lmax; }
    __syncthreads();
    if (tid == 0) {
        sum_m[b]  = rsum[0]+rsum[1]+rsum[2]+rsum[3];
        tl_o[b]   = rtl[0]+rtl[1]+rtl[2]+rtl[3];
        slab_o[b] = fmaxf(fmaxf(rsl[0],rsl[1]), fmaxf(rsl[2],rsl[3]));
        mino_o[b] = fminf(fminf(rmn[0],rmn[1]), fminf(rmn[2],rmn[3]));
        maxm_o[b] = fmaxf(fmaxf(rmx[0],rmx[1]), fmaxf(rmx[2],rmx[3]));
    }
}

// ---------------------------------------------------------------------------
// K3: pooled[b,:] += sum_s h[b,s,:] * masked[b,s]/sum_m[b] over a 16-row
// s-chunk. grid (64 b, 32 sc) x 192 threads, fully coalesced.
// fp32 atomicAdd partials (32-way per address, pipelined through L2).
// ---------------------------------------------------------------------------
__global__ __launch_bounds__(192) void k3_pool(
    const float* __restrict__ h, const float* __restrict__ masked,
    const float* __restrict__ sum_m, float* __restrict__ pooled)
{
    const int b = blockIdx.x, sc = blockIdx.y;
    const int tid = threadIdx.x;
    __shared__ float nrm[16];
    if (tid < 16)
        nrm[tid] = masked[b * Sn + sc * 16 + tid] * (1.0f / sum_m[b]);
    __syncthreads();
    const floatx4* hp = (const floatx4*)(h + ((size_t)b * Sn + sc * 16) * Hn) + tid;
    float ax = 0.f, ay = 0.f, az = 0.f, aw = 0.f;
    #pragma unroll 8
    for (int s = 0; s < 16; s++) {
        floatx4 v = hp[(size_t)s * (Hn / 4)];
        float w = nrm[s];
        ax += v.x * w; ay += v.y * w; az += v.z * w; aw += v.w * w;
    }
    float* pp = pooled + (size_t)b * Hn + tid * 4;
    atomicAdd(pp + 0, ax); atomicAdd(pp + 1, ay);
    atomicAdd(pp + 2, az); atomicAdd(pp + 3, aw);
}

// ---------------------------------------------------------------------------
// K4: zpart[jc,b] = sum_{j in chunk} tanh(pooled[b]·W3T[j] + b3[j]) * W4[j].
// grid (64 b, 5 jc) x 256 threads; 4 threads per j, float4 dot over k.
// ---------------------------------------------------------------------------
__global__ __launch_bounds__(256) void k4_sent(
    const float* __restrict__ pooled, const float* __restrict__ w3t,
    const float* __restrict__ b3, const float* __restrict__ W4,
    float* __restrict__ zpart)
{
    const int b = blockIdx.x, jc = blockIdx.y;
    const int tid = threadIdx.x;
    __shared__ __align__(16) float pl[Hn];
    __shared__ float yred[64];
    for (int k = tid; k < Hn; k += 256) pl[k] = pooled[(size_t)b * Hn + k];
    if (tid < 64) yred[tid] = 0.f;
    __syncthreads();
    int jj = tid >> 2, ks = tid & 3;
    float a = 0.f;
    if (jj < 60) {
        int j = jc * 60 + jj;
        const floatx4* wr = (const floatx4*)(w3t + (size_t)j * Hn) + ks * 48;
        const floatx4* pr = (const floatx4*)pl + ks * 48;
        #pragma unroll 8
        for (int i = 0; i < 48; i++) {
            floatx4 wv = wr[i]; floatx4 pv = pr[i];
            a += wv.x * pv.x + wv.y * pv.y + wv.z * pv.z + wv.w * pv.w;
        }
    }
    a += __shfl_xor(a, 1, 64);
    a += __shfl_xor(a, 2, 64);
    if (jj < 60 && ks == 0) {
        int j = jc * 60 + jj;
        yred[jj] = tanhf(a + b3[j]) * W4[j];
    }
    __syncthreads();
    if (tid < 64) {
        float y = yred[tid];
        y = wred_sum(y);
        if (tid == 0) zpart[jc * Bn + b] = y;
    }
}

// ---------------------------------------------------------------------------
// K5: sent + final scalars. One wave; b = lane.
// ---------------------------------------------------------------------------
__global__ __launch_bounds__(64) void k5_loss(
    const float* __restrict__ zpart, const float* __restrict__ b4,
    const float* __restrict__ slab, const float* __restrict__ tl,
    const float* __restrict__ mino, const float* __restrict__ maxm,
    float* __restrict__ out, float* __restrict__ out_sent)
{
    int t = threadIdx.x;
    float z = b4[0];
    #pragma unroll
    for (int jc = 0; jc < 5; jc++) z += zpart[jc * Bn + t];
    float sent = sigf(z);
    out_sent[t] = sent;
    float sl = slab[t];
    float e1 = (sent - sl) * (sent - sl);
    float e2 = tl[t];
    float e3 = mino[t] * mino[t];
    float mm = maxm[t] - sl;
    float e4 = mm * mm;
    e1 = wred_sum(e1); e2 = wred_sum(e2); e3 = wred_sum(e3); e4 = wred_sum(e4);
    if (t == 0) {
        out[1] = e1;
        out[2] = e2;
        out[3] = e3;
        out[4] = e4;
        out[0] = e1 + e2 + 0.01f * (e3 + e4);
    }
}

extern "C" void kernel_launch(void* const* d_in, const int* in_sizes, int n_in,
                              void* d_out, int out_size, void* d_ws, size_t ws_size,
                              hipStream_t stream) {
    (void)in_sizes; (void)n_in; (void)out_size; (void)ws_size;
    const float* h      = (const float*)d_in[0];
    const int*   offset = (const int*)d_in[1];
    const float* labels = (const float*)d_in[2];
    const float* W1     = (const float*)d_in[3];
    const float* b1     = (const float*)d_in[4];
    const float* W2     = (const float*)d_in[5];
    const float* b2     = (const float*)d_in[6];
    const float* W3     = (const float*)d_in[7];
    const float* b3     = (const float*)d_in[8];
    const float* W4     = (const float*)d_in[9];
    const float* b4     = (const float*)d_in[10];

    float* out        = (float*)d_out;
    float* out_hidden = out + 5;
    float* out_masked = out_hidden + (size_t)Bn * Sn * Hn;   // 25,165,824
    float* out_sent   = out_masked + (size_t)Bn * Sn;        // 32,768

    float* ws      = (float*)d_ws;
    float* att     = ws;                        // 32768
    float* sum_m   = att + Mtok;                // 64
    float* slab    = sum_m + Bn;
    float* tlb     = slab + Bn;
    float* mino    = tlb + Bn;
    float* maxm    = mino + Bn;
    float* pooled  = maxm + Bn;                 // 49152
    float* zpart   = pooled + POOL_N;           // 320
    float* b1w2    = zpart + 5 * Bn;            // 224
    float* w3t     = b1w2 + 2 * NP;             // 230400
    unsigned short* w1t = (unsigned short*)(w3t + W3T_N);  // 86016 bf16

    int k0_total = W1T_N + W3T_N + NP + POOL_N + 5 * Bn;
    k0_prep<<<(k0_total + 255) / 256, 256, 0, stream>>>(W1, b1, W2, W3,
                                                        w1t, b1w2, w3t, pooled, zpart);
    k1_att<<<Mtok / 64, 256, 0, stream>>>(h, w1t, b1w2, b2, out_hidden, att);
    k2_seg<<<Bn, 256, 0, stream>>>(att, offset, labels, out_masked,
                                   sum_m, slab, tlb, mino, maxm);
    k3_pool<<<dim3(Bn, 32), 192, 0, stream>>>(h, out_masked, sum_m, pooled);
    k4_sent<<<dim3(Bn, 5), 256, 0, stream>>>(pooled, w3t, b3, W4, zpart);
    k5_loss<<<1, 64, 0, stream>>>(zpart, b4, slab, tlb, mino, maxm, out, out_sent);
}

// Round 5
// 289.734 us; speedup vs baseline: 1.1825x; 1.1678x over previous
//
#include <hip/hip_runtime.h>
#include <math.h>

#define Bn 64
#define Sn 512
#define Hn 768
#define ATT_H 100
#define CLS_H 300
#define Mtok (Bn*Sn)          // 32768
#define NP 112                // padded ATT_H (7 x 16)
#define NT 7                  // col tiles of 16

#define W1T_N (NP*Hn)         // 86016 (fragment-ordered bf16)
#define W3T_N (CLS_H*Hn)      // 230400
#define NSG 16                // k3 s-groups (partials per batch row)

typedef __attribute__((ext_vector_type(8))) short short8;
typedef __attribute__((ext_vector_type(4))) float floatx4;

__device__ inline float sigf(float x) { return 1.0f / (1.0f + expf(-x)); }

__device__ inline unsigned short f2bf(float x) {
    union { float f; unsigned int u; } v; v.f = x;
    unsigned int r = (v.u + 0x7FFFu + ((v.u >> 16) & 1u)) >> 16;
    return (unsigned short)r;
}

__device__ inline float wred_sum(float v) {
    #pragma unroll
    for (int d = 32; d; d >>= 1) v += __shfl_down(v, d, 64);
    return v;
}
__device__ inline float wred_max(float v) {
    #pragma unroll
    for (int d = 32; d; d >>= 1) v = fmaxf(v, __shfl_down(v, d, 64));
    return v;
}
__device__ inline float wred_min(float v) {
    #pragma unroll
    for (int d = 32; d; d >>= 1) v = fminf(v, __shfl_down(v, d, 64));
    return v;
}

// ---------------------------------------------------------------------------
// K0: prep.
// w1t FRAGMENT-ORDERED bf16: w1t[((kstep*7 + ct)*64 + lane)*8 + e]
//   = W1[k][n], n = ct*16 + (lane&15), k = kstep*32 + (lane>>4)*8 + e,
//   zero-padded for n >= ATT_H.
// w3t[j][k] = W3[k][j]; b1w2[n] = (b1[n], W2[n]).
// (pooled/zpart zero-init dropped: k4 now sums k3 partials directly and
//  fully writes zpart.)
// ---------------------------------------------------------------------------
__global__ __launch_bounds__(256) void k0_prep(
    const float* __restrict__ W1, const float* __restrict__ b1,
    const float* __restrict__ W2, const float* __restrict__ W3,
    unsigned short* __restrict__ w1t, float* __restrict__ b1w2,
    float* __restrict__ w3t)
{
    int idx = blockIdx.x * 256 + threadIdx.x;
    if (idx < W1T_N) {
        int e = idx & 7;
        int lane = (idx >> 3) & 63;
        int t = idx >> 9;                 // kstep*7 + ct
        int ct = t % 7, kstep = t / 7;
        int n = ct * 16 + (lane & 15);
        int k = kstep * 32 + (lane >> 4) * 8 + e;
        float v = (n < ATT_H) ? W1[(size_t)k * ATT_H + n] : 0.f;
        w1t[idx] = f2bf(v);
    } else if (idx < W1T_N + W3T_N) {
        int i = idx - W1T_N;
        int j = i / Hn, k = i - j * Hn;
        w3t[i] = W3[(size_t)k * CLS_H + j];
    } else if (idx < W1T_N + W3T_N + NP) {
        int j = idx - (W1T_N + W3T_N);
        b1w2[2 * j]     = (j < ATT_H) ? b1[j] : 0.f;
        b1w2[2 * j + 1] = (j < ATT_H) ? W2[j] : 0.f;
    }
}

// ---------------------------------------------------------------------------
// K1 (v6): R2's proven port-roofline structure + M-reuse x2, no-spill.
// R3/R4 post-mortem: acc arrays beyond ~56 regs + launch-bounds mismatch ->
// scratch spills (+59 MB write = exactly 56 regs x 256 thr x 1024 blk).
// v6: block = 32 tokens (2 M-tiles), 4 waves = 4 k-quarters (192 k each);
// each wave computes BOTH M-tiles from the same B fragment (B-traffic
// 344 -> 172 MB; total port bytes ~372 MB -> ~62 us at R2's measured
// 5.8 TB/s port ceiling). Register budget: acc0[7]+acc1[7] = 56 (AGPR) +
// ~90 VGPR -> __launch_bounds__(256,3) (cap ~170, 12 waves/CU, R2's
// effective occupancy). LDS: R3's measured-conflict-free geometry
// (128 B rows, XOR swizzle byte^=(row&7)<<4), wave-private, double-
// buffered, no barriers in the main loop. Pipeline: pack(ch) ->
// prefetch(ch+1) -> compute(ch), only v[8] double-buffered in regs.
// Combine: 4-way through LDS, fully unrolled, named acc arrays only.
// ---------------------------------------------------------------------------
__global__ __launch_bounds__(256, 3) void k1_att(
    const float* __restrict__ h, const unsigned short* __restrict__ w1t,
    const float* __restrict__ b1w2, const float* __restrict__ b2,
    float* __restrict__ out_hidden, float* __restrict__ att)
{
    // 4 waves x dbuf x (32 rows x 128 B) = 32768 B; reused as combine buffer.
    __shared__ __align__(16) char smem[32768];

    const int tid = threadIdx.x;
    const int wave = tid >> 6, lane = tid & 63;
    const int u = lane & 15, q = lane >> 4;
    const int g = wave;                    // k-quarter 0..3
    const int tok0 = blockIdx.x * 32;

    const int lr = lane >> 4;              // staging row-within-quad 0..3
    const int lcb = (lane & 15) * 8;       // staging byte col (bf16 row = 128 B)

    floatx4 acc0[NT], acc1[NT];
    #pragma unroll
    for (int ct = 0; ct < NT; ct++) { acc0[ct] = (floatx4)0.f; acc1[ct] = (floatx4)0.f; }

    const short8* __restrict__ w1f = (const short8*)w1t;
    char* const sb = smem + wave * 8192;

    floatx4 v[8];
    // prologue: chunk 0 loads (32 rows x 64 cols, coalesced float4)
    #pragma unroll
    for (int j = 0; j < 8; j++) {
        size_t gidx = (size_t)(tok0 + j * 4 + lr) * Hn + g * 192 + lcb / 2;
        v[j] = *(const floatx4*)(h + gidx);
    }

    #pragma unroll
    for (int ch = 0; ch < 3; ch++) {
        char* stage = sb + (ch & 1) * 4096;
        const int kbase = g * 192 + ch * 64;

        // pack chunk ch: passthrough store + bf16 -> swizzled wave-private LDS
        #pragma unroll
        for (int j = 0; j < 8; j++) {
            int row = j * 4 + lr;
            size_t gidx = (size_t)(tok0 + row) * Hn + kbase + lcb / 2;
            *(floatx4*)(out_hidden + gidx) = v[j];
            ushort4 bv;
            bv.x = f2bf(v[j].x); bv.y = f2bf(v[j].y);
            bv.z = f2bf(v[j].z); bv.w = f2bf(v[j].w);
            *(ushort4*)(stage + row * 128 + (lcb ^ ((row & 7) << 4))) = bv;
        }

        // prefetch chunk ch+1 (in flight during compute below)
        if (ch < 2) {
            #pragma unroll
            for (int j = 0; j < 8; j++) {
                size_t gidx = (size_t)(tok0 + j * 4 + lr) * Hn + kbase + 64 + lcb / 2;
                v[j] = *(const floatx4*)(h + gidx);
            }
        }

        // compute chunk ch: 2 k-steps x 7 ct, both M-tiles per B fragment
        #pragma unroll
        for (int ks = 0; ks < 2; ks++) {
            const int kstep = g * 6 + ch * 2 + ks;
            short8 a0 = *(const short8*)(stage + u * 128
                                         + ((ks * 64 + q * 16) ^ ((u & 7) << 4)));
            short8 a1 = *(const short8*)(stage + (16 + u) * 128
                                         + ((ks * 64 + q * 16) ^ ((u & 7) << 4)));
            #pragma unroll
            for (int ct = 0; ct < NT; ct++) {
                short8 bfr = w1f[(kstep * 7 + ct) * 64 + lane];
                acc0[ct] = __builtin_amdgcn_mfma_f32_16x16x32_bf16(a0, bfr, acc0[ct], 0, 0, 0);
                acc1[ct] = __builtin_amdgcn_mfma_f32_16x16x32_bf16(a1, bfr, acc1[ct], 0, 0, 0);
            }
        }
    }

    // 4-way k-combine + epilogue, per M-tile; fully static indexing.
    float* cb = (float*)smem;     // 3*64*28 = 5376 floats = 21504 B
    // ---- M-tile 0 (tokens tok0 .. tok0+15), acc0 ----
    __syncthreads();
    if (g > 0) {
        #pragma unroll
        for (int ct = 0; ct < NT; ct++)
            *(floatx4*)(&cb[((g - 1) * 64 + lane) * 28 + ct * 4]) = acc0[ct];
    }
    __syncthreads();
    if (g == 0) {
        #pragma unroll
        for (int o = 0; o < 3; o++)
            #pragma unroll
            for (int ct = 0; ct < NT; ct++)
                acc0[ct] += *(const floatx4*)(&cb[(o * 64 + lane) * 28 + ct * 4]);
        float z[4] = {0.f, 0.f, 0.f, 0.f};
        #pragma unroll
        for (int ct = 0; ct < NT; ct++) {
            float2 bw = *(const float2*)(b1w2 + (ct * 16 + u) * 2);
            #pragma unroll
            for (int r = 0; r < 4; r++)
                z[r] += tanhf(acc0[ct][r] + bw.x) * bw.y;
        }
        #pragma unroll
        for (int mask = 1; mask < 16; mask <<= 1) {
            #pragma unroll
            for (int r = 0; r < 4; r++) z[r] += __shfl_xor(z[r], mask, 64);
        }
        if (u == 0) {
            float bb2 = b2[0];
            #pragma unroll
            for (int r = 0; r < 4; r++)
                att[tok0 + q * 4 + r] = sigf(z[r] + bb2);
        }
    }
    // ---- M-tile 1 (tokens tok0+16 .. tok0+31), acc1 ----
    __syncthreads();
    if (g > 0) {
        #pragma unroll
        for (int ct = 0; ct < NT; ct++)
            *(floatx4*)(&cb[((g - 1) * 64 + lane) * 28 + ct * 4]) = acc1[ct];
    }
    __syncthreads();
    if (g == 0) {
        #pragma unroll
        for (int o = 0; o < 3; o++)
            #pragma unroll
            for (int ct = 0; ct < NT; ct++)
                acc1[ct] += *(const floatx4*)(&cb[(o * 64 + lane) * 28 + ct * 4]);
        float z[4] = {0.f, 0.f, 0.f, 0.f};
        #pragma unroll
        for (int ct = 0; ct < NT; ct++) {
            float2 bw = *(const float2*)(b1w2 + (ct * 16 + u) * 2);
            #pragma unroll
            for (int r = 0; r < 4; r++)
                z[r] += tanhf(acc1[ct][r] + bw.x) * bw.y;
        }
        #pragma unroll
        for (int mask = 1; mask < 16; mask <<= 1) {
            #pragma unroll
            for (int r = 0; r < 4; r++) z[r] += __shfl_xor(z[r], mask, 64);
        }
        if (u == 0) {
            float bb2 = b2[0];
            #pragma unroll
            for (int r = 0; r < 4; r++)
                att[tok0 + 16 + q * 4 + r] = sigf(z[r] + bb2);
        }
    }
}

// ---------------------------------------------------------------------------
// K2: per batch row — word max via direct forward chase; one pass, one
// barrier. Reductions unchanged. (verified R1-R4)
// ---------------------------------------------------------------------------
__global__ __launch_bounds__(256) void k2_seg(
    const float* __restrict__ att, const int* __restrict__ offset,
    const float* __restrict__ labels, float* __restrict__ masked_out,
    float* __restrict__ sum_m, float* __restrict__ slab_o,
    float* __restrict__ tl_o, float* __restrict__ mino_o,
    float* __restrict__ maxm_o)
{
    const int b = blockIdx.x, tid = threadIdx.x;
    __shared__ float attl[Sn];
    __shared__ int   startl[Sn];
    __shared__ float rsum[4], rtl[4], rsl[4], rmn[4], rmx[4];

    for (int s = tid; s < Sn; s += 256) {
        attl[s] = att[b * Sn + s];
        startl[s] = (offset[(size_t)(b * Sn + s) * 2] == 0) ? 1 : 0;
    }
    __syncthreads();

    float lsum = 0.f, ltl = 0.f, lslab = -1e30f, lmin = 1e30f, lmax = -1e30f;
    for (int s = tid; s < Sn; s += 256) {
        float lab = labels[b * Sn + s];
        int st = startl[s];
        float m = 0.f;
        if (st && lab != -1.0f) {
            m = attl[s];
            for (int t = s + 1; t < Sn && !startl[t]; t++)
                m = fmaxf(m, attl[t]);
        }
        masked_out[b * Sn + s] = m;
        lsum += m;
        float zl = (lab == 1.0f) ? 1.f : 0.f;
        ltl += (m - zl) * (m - zl);
        lslab = fmaxf(lslab, lab);
        float om = (m == 0.f) ? 1.f : m;
        lmin = fminf(lmin, om);
        lmax = fmaxf(lmax, m);
    }
    int wid = tid >> 6, lane = tid & 63;
    lsum = wred_sum(lsum); ltl = wred_sum(ltl);
    lslab = wred_max(lslab); lmin = wred_min(lmin); lmax = wred_max(lmax);
    if (lane == 0) { rsum[wid]=lsum; rtl[wid]=ltl; rsl[wid]=lslab; rmn[wid]=lmin; rmx[wid]=lmax; }
    __syncthreads();
    if (tid == 0) {
        sum_m[b]  = rsum[0]+rsum[1]+rsum[2]+rsum[3];
        tl_o[b]   = rtl[0]+rtl[1]+rtl[2]+rtl[3];
        slab_o[b] = fmaxf(fmaxf(rsl[0],rsl[1]), fmaxf(rsl[2],rsl[3]));
        mino_o[b] = fminf(fminf(rmn[0],rmn[1]), fminf(rmn[2],rmn[3]));
        maxm_o[b] = fmaxf(fmaxf(rmx[0],rmx[1]), fmaxf(rmx[2],rmx[3]));
    }
}

// ---------------------------------------------------------------------------
// K3 (v2): partial pooled sums, NO atomics. grid (64 b, 16 sg) x 192 thr;
// each block reduces 32 s-rows and writes part[b][sg][768] with plain
// coalesced float4 stores. (R4 suspect: 1.57M fp32 atomicAdds with 32-way
// same-address contention; partials remove them and the zero-init dep.)
// ---------------------------------------------------------------------------
__global__ __launch_bounds__(192) void k3_pool(
    const float* __restrict__ h, const float* __restrict__ masked,
    const float* __restrict__ sum_m, float* __restrict__ part)
{
    const int b = blockIdx.x, sg = blockIdx.y;
    const int tid = threadIdx.x;
    __shared__ float nrm[32];
    if (tid < 32)
        nrm[tid] = masked[b * Sn + sg * 32 + tid] * (1.0f / sum_m[b]);
    __syncthreads();
    const floatx4* hp = (const floatx4*)(h + ((size_t)b * Sn + sg * 32) * Hn) + tid;
    float ax = 0.f, ay = 0.f, az = 0.f, aw = 0.f;
    #pragma unroll 8
    for (int s = 0; s < 32; s++) {
        floatx4 v = hp[(size_t)s * (Hn / 4)];
        float w = nrm[s];
        ax += v.x * w; ay += v.y * w; az += v.z * w; aw += v.w * w;
    }
    floatx4 o; o.x = ax; o.y = ay; o.z = az; o.w = aw;
    *(floatx4*)(part + ((size_t)b * NSG + sg) * Hn + tid * 4) = o;
}

// ---------------------------------------------------------------------------
// K4: zpart[jc,b] = sum_{j in chunk} tanh(pooled[b]·W3T[j] + b3[j]) * W4[j].
// Prologue now sums the 16 k3 partials into pl[] (96 KB L2 per block).
// grid (64 b, 5 jc) x 256 threads; 4 threads per j, float4 dot over k.
// ---------------------------------------------------------------------------
__global__ __launch_bounds__(256) void k4_sent(
    const float* __restrict__ part, const float* __restrict__ w3t,
    const float* __restrict__ b3, const float* __restrict__ W4,
    float* __restrict__ zpart)
{
    const int b = blockIdx.x, jc = blockIdx.y;
    const int tid = threadIdx.x;
    __shared__ __align__(16) float pl[Hn];
    __shared__ float yred[64];
    for (int k = tid; k < Hn; k += 256) {
        float s = 0.f;
        #pragma unroll
        for (int g = 0; g < NSG; g++)
            s += part[((size_t)b * NSG + g) * Hn + k];
        pl[k] = s;
    }
    if (tid < 64) yred[tid] = 0.f;
    __syncthreads();
    int jj = tid >> 2, ks = tid & 3;
    float a = 0.f;
    if (jj < 60) {
        int j = jc * 60 + jj;
        const floatx4* wr = (const floatx4*)(w3t + (size_t)j * Hn) + ks * 48;
        const floatx4* pr = (const floatx4*)pl + ks * 48;
        #pragma unroll 8
        for (int i = 0; i < 48; i++) {
            floatx4 wv = wr[i]; floatx4 pv = pr[i];
            a += wv.x * pv.x + wv.y * pv.y + wv.z * pv.z + wv.w * pv.w;
        }
    }
    a += __shfl_xor(a, 1, 64);
    a += __shfl_xor(a, 2, 64);
    if (jj < 60 && ks == 0) {
        int j = jc * 60 + jj;
        yred[jj] = tanhf(a + b3[j]) * W4[j];
    }
    __syncthreads();
    if (tid < 64) {
        float y = yred[tid];
        y = wred_sum(y);
        if (tid == 0) zpart[jc * Bn + b] = y;
    }
}

// ---------------------------------------------------------------------------
// K5: sent + final scalars. One wave; b = lane.
// ---------------------------------------------------------------------------
__global__ __launch_bounds__(64) void k5_loss(
    const float* __restrict__ zpart, const float* __restrict__ b4,
    const float* __restrict__ slab, const float* __restrict__ tl,
    const float* __restrict__ mino, const float* __restrict__ maxm,
    float* __restrict__ out, float* __restrict__ out_sent)
{
    int t = threadIdx.x;
    float z = b4[0];
    #pragma unroll
    for (int jc = 0; jc < 5; jc++) z += zpart[jc * Bn + t];
    float sent = sigf(z);
    out_sent[t] = sent;
    float sl = slab[t];
    float e1 = (sent - sl) * (sent - sl);
    float e2 = tl[t];
    float e3 = mino[t] * mino[t];
    float mm = maxm[t] - sl;
    float e4 = mm * mm;
    e1 = wred_sum(e1); e2 = wred_sum(e2); e3 = wred_sum(e3); e4 = wred_sum(e4);
    if (t == 0) {
        out[1] = e1;
        out[2] = e2;
        out[3] = e3;
        out[4] = e4;
        out[0] = e1 + e2 + 0.01f * (e3 + e4);
    }
}

extern "C" void kernel_launch(void* const* d_in, const int* in_sizes, int n_in,
                              void* d_out, int out_size, void* d_ws, size_t ws_size,
                              hipStream_t stream) {
    (void)in_sizes; (void)n_in; (void)out_size; (void)ws_size;
    const float* h      = (const float*)d_in[0];
    const int*   offset = (const int*)d_in[1];
    const float* labels = (const float*)d_in[2];
    const float* W1     = (const float*)d_in[3];
    const float* b1     = (const float*)d_in[4];
    const float* W2     = (const float*)d_in[5];
    const float* b2     = (const float*)d_in[6];
    const float* W3     = (const float*)d_in[7];
    const float* b3     = (const float*)d_in[8];
    const float* W4     = (const float*)d_in[9];
    const float* b4     = (const float*)d_in[10];

    float* out        = (float*)d_out;
    float* out_hidden = out + 5;
    float* out_masked = out_hidden + (size_t)Bn * Sn * Hn;   // 25,165,824
    float* out_sent   = out_masked + (size_t)Bn * Sn;        // 32,768

    float* ws      = (float*)d_ws;
    float* att     = ws;                        // 32768
    float* sum_m   = att + Mtok;                // 64
    float* slab    = sum_m + Bn;
    float* tlb     = slab + Bn;
    float* mino    = tlb + Bn;
    float* maxm    = mino + Bn;
    float* part    = maxm + Bn;                 // 64*16*768 = 786432
    float* zpart   = part + (size_t)Bn * NSG * Hn;  // 320
    float* b1w2    = zpart + 5 * Bn;            // 224
    float* w3t     = b1w2 + 2 * NP;             // 230400
    unsigned short* w1t = (unsigned short*)(w3t + W3T_N);  // 86016 bf16

    int k0_total = W1T_N + W3T_N + NP;
    k0_prep<<<(k0_total + 255) / 256, 256, 0, stream>>>(W1, b1, W2, W3,
                                                        w1t, b1w2, w3t);
    k1_att<<<Mtok / 32, 256, 0, stream>>>(h, w1t, b1w2, b2, out_hidden, att);
    k2_seg<<<Bn, 256, 0, stream>>>(att, offset, labels, out_masked,
                                   sum_m, slab, tlb, mino, maxm);
    k3_pool<<<dim3(Bn, NSG), 192, 0, stream>>>(h, out_masked, sum_m, part);
    k4_sent<<<dim3(Bn, 5), 256, 0, stream>>>(part, w3t, b3, W4, zpart);
    k5_loss<<<1, 64, 0, stream>>>(zpart, b4, slab, tlb, mino, maxm, out, out_sent);
}

// Round 6
// 257.262 us; speedup vs baseline: 1.3318x; 1.1262x over previous
//
#include <hip/hip_runtime.h>
#include <math.h>

#define Bn 64
#define Sn 512
#define Hn 768
#define ATT_H 100
#define CLS_H 300
#define Mtok (Bn*Sn)          // 32768
#define NP 112                // padded ATT_H (7 x 16)
#define NT 7                  // col tiles of 16

#define W1T_N (NP*Hn)         // 86016 (fragment-ordered bf16)
#define W3T_N (CLS_H*Hn)      // 230400
#define NSG 16                // k3 s-groups (partials per batch row)

typedef __attribute__((ext_vector_type(8))) short short8;
typedef __attribute__((ext_vector_type(4))) float floatx4;

__device__ inline float sigf(float x) { return 1.0f / (1.0f + expf(-x)); }

__device__ inline unsigned short f2bf(float x) {
    union { float f; unsigned int u; } v; v.f = x;
    unsigned int r = (v.u + 0x7FFFu + ((v.u >> 16) & 1u)) >> 16;
    return (unsigned short)r;
}

__device__ inline float wred_sum(float v) {
    #pragma unroll
    for (int d = 32; d; d >>= 1) v += __shfl_down(v, d, 64);
    return v;
}
__device__ inline float wred_max(float v) {
    #pragma unroll
    for (int d = 32; d; d >>= 1) v = fmaxf(v, __shfl_down(v, d, 64));
    return v;
}
__device__ inline float wred_min(float v) {
    #pragma unroll
    for (int d = 32; d; d >>= 1) v = fminf(v, __shfl_down(v, d, 64));
    return v;
}

// ---------------------------------------------------------------------------
// K0 (v2): prep with COALESCED READS + scatter writes (stores are
// fire-and-forget; the old version's stride-400B/1200B gather reads were
// the latency chain).
//   range A [0, W1T_N): zero-fill ONLY the pad slots of w1t (n >= ATT_H).
//   range B: read W1[i] coalesced (i = k*ATT_H+n), scatter to fragment slot.
//   range C: read W3[i] coalesced (i = k*CLS_H+j), scatter to w3t[j*Hn+k].
//   range D: b1w2.
// w1t FRAGMENT-ORDERED bf16: w1t[((kstep*7+ct)*64 + (q*16+u))*8 + e]
//   = W1[k][n], n = ct*16+u, k = kstep*32 + q*8 + e.
// ---------------------------------------------------------------------------
__global__ __launch_bounds__(256) void k0_prep(
    const float* __restrict__ W1, const float* __restrict__ b1,
    const float* __restrict__ W2, const float* __restrict__ W3,
    unsigned short* __restrict__ w1t, float* __restrict__ b1w2,
    float* __restrict__ w3t)
{
    int idx = blockIdx.x * 256 + threadIdx.x;
    if (idx < W1T_N) {
        // zero-fill pad slots only (n >= ATT_H); real values written below
        int lane = (idx >> 3) & 63;
        int t = idx >> 9;                 // kstep*7 + ct
        int ct = t % 7;
        int n = ct * 16 + (lane & 15);
        if (n >= ATT_H) w1t[idx] = 0;
    } else if (idx < W1T_N + Hn * ATT_H) {
        int i = idx - W1T_N;              // i = k*ATT_H + n, coalesced read
        int k = i / ATT_H, n = i - k * ATT_H;
        int ct = n >> 4, u = n & 15;
        int kstep = k >> 5, q = (k & 31) >> 3, e = k & 7;
        w1t[((kstep * 7 + ct) * 64 + (q * 16 + u)) * 8 + e] = f2bf(W1[i]);
    } else if (idx < W1T_N + Hn * ATT_H + W3T_N) {
        int i = idx - (W1T_N + Hn * ATT_H);   // i = k*CLS_H + j, coalesced
        int k = i / CLS_H, j = i - k * CLS_H;
        w3t[(size_t)j * Hn + k] = W3[i];
    } else if (idx < W1T_N + Hn * ATT_H + W3T_N + NP) {
        int j = idx - (W1T_N + Hn * ATT_H + W3T_N);
        b1w2[2 * j]     = (j < ATT_H) ? b1[j] : 0.f;
        b1w2[2 * j + 1] = (j < ATT_H) ? W2[j] : 0.f;
    }
}

// ---------------------------------------------------------------------------
// K1 (v7): READ-ONLY main loop. R2-R5 post-mortem: dur tracked
// WRITE_SIZE/1.16 TB/s across all variants -- the passthrough stores shared
// the vmcnt queue with prefetch loads (3-deep pipeline, ~19 KB/CU in
// flight < the ~22 KB needed for full BW) and their drain stalled each
// chunk. The passthrough h->out_hidden copy is MOVED TO K3 (which re-reads
// h anyway, making it a pure-stream copy). k1 keeps R5's proven geometry:
// block = 32 tokens (2 M-tiles), 4 waves = 4 k-quarters, B-reuse x2,
// wave-private dbuf LDS (128 B rows, XOR swizzle byte^=(row&7)<<4,
// measured 0 conflicts), no barriers in the main loop, no spills
// (acc0[7]+acc1[7]=56 + ~30 live, launch_bounds(256,3)).
// ---------------------------------------------------------------------------
__global__ __launch_bounds__(256, 3) void k1_att(
    const float* __restrict__ h, const unsigned short* __restrict__ w1t,
    const float* __restrict__ b1w2, const float* __restrict__ b2,
    float* __restrict__ att)
{
    // 4 waves x dbuf x (32 rows x 128 B) = 32768 B; reused as combine buffer.
    __shared__ __align__(16) char smem[32768];

    const int tid = threadIdx.x;
    const int wave = tid >> 6, lane = tid & 63;
    const int u = lane & 15, q = lane >> 4;
    const int g = wave;                    // k-quarter 0..3
    const int tok0 = blockIdx.x * 32;

    const int lr = lane >> 4;              // staging row-within-quad 0..3
    const int lcb = (lane & 15) * 8;       // staging byte col (bf16 row = 128 B)

    floatx4 acc0[NT], acc1[NT];
    #pragma unroll
    for (int ct = 0; ct < NT; ct++) { acc0[ct] = (floatx4)0.f; acc1[ct] = (floatx4)0.f; }

    const short8* __restrict__ w1f = (const short8*)w1t;
    char* const sb = smem + wave * 8192;

    floatx4 v[8];
    // prologue: chunk 0 loads (32 rows x 64 cols, coalesced float4)
    #pragma unroll
    for (int j = 0; j < 8; j++) {
        size_t gidx = (size_t)(tok0 + j * 4 + lr) * Hn + g * 192 + lcb / 2;
        v[j] = *(const floatx4*)(h + gidx);
    }

    #pragma unroll
    for (int ch = 0; ch < 3; ch++) {
        char* stage = sb + (ch & 1) * 4096;

        // pack chunk ch: bf16 -> swizzled wave-private LDS (no global store)
        #pragma unroll
        for (int j = 0; j < 8; j++) {
            int row = j * 4 + lr;
            ushort4 bv;
            bv.x = f2bf(v[j].x); bv.y = f2bf(v[j].y);
            bv.z = f2bf(v[j].z); bv.w = f2bf(v[j].w);
            *(ushort4*)(stage + row * 128 + (lcb ^ ((row & 7) << 4))) = bv;
        }

        // prefetch chunk ch+1 (in flight during compute below)
        if (ch < 2) {
            const int kbase = g * 192 + ch * 64;
            #pragma unroll
            for (int j = 0; j < 8; j++) {
                size_t gidx = (size_t)(tok0 + j * 4 + lr) * Hn + kbase + 64 + lcb / 2;
                v[j] = *(const floatx4*)(h + gidx);
            }
        }

        // compute chunk ch: 2 k-steps x 7 ct, both M-tiles per B fragment
        #pragma unroll
        for (int ks = 0; ks < 2; ks++) {
            const int kstep = g * 6 + ch * 2 + ks;
            short8 a0 = *(const short8*)(stage + u * 128
                                         + ((ks * 64 + q * 16) ^ ((u & 7) << 4)));
            short8 a1 = *(const short8*)(stage + (16 + u) * 128
                                         + ((ks * 64 + q * 16) ^ ((u & 7) << 4)));
            #pragma unroll
            for (int ct = 0; ct < NT; ct++) {
                short8 bfr = w1f[(kstep * 7 + ct) * 64 + lane];
                acc0[ct] = __builtin_amdgcn_mfma_f32_16x16x32_bf16(a0, bfr, acc0[ct], 0, 0, 0);
                acc1[ct] = __builtin_amdgcn_mfma_f32_16x16x32_bf16(a1, bfr, acc1[ct], 0, 0, 0);
            }
        }
    }

    // 4-way k-combine + epilogue, per M-tile; fully static indexing.
    float* cb = (float*)smem;     // 3*64*28 = 5376 floats = 21504 B
    // ---- M-tile 0 (tokens tok0 .. tok0+15), acc0 ----
    __syncthreads();
    if (g > 0) {
        #pragma unroll
        for (int ct = 0; ct < NT; ct++)
            *(floatx4*)(&cb[((g - 1) * 64 + lane) * 28 + ct * 4]) = acc0[ct];
    }
    __syncthreads();
    if (g == 0) {
        #pragma unroll
        for (int o = 0; o < 3; o++)
            #pragma unroll
            for (int ct = 0; ct < NT; ct++)
                acc0[ct] += *(const floatx4*)(&cb[(o * 64 + lane) * 28 + ct * 4]);
        float z[4] = {0.f, 0.f, 0.f, 0.f};
        #pragma unroll
        for (int ct = 0; ct < NT; ct++) {
            float2 bw = *(const float2*)(b1w2 + (ct * 16 + u) * 2);
            #pragma unroll
            for (int r = 0; r < 4; r++)
                z[r] += tanhf(acc0[ct][r] + bw.x) * bw.y;
        }
        #pragma unroll
        for (int mask = 1; mask < 16; mask <<= 1) {
            #pragma unroll
            for (int r = 0; r < 4; r++) z[r] += __shfl_xor(z[r], mask, 64);
        }
        if (u == 0) {
            float bb2 = b2[0];
            #pragma unroll
            for (int r = 0; r < 4; r++)
                att[tok0 + q * 4 + r] = sigf(z[r] + bb2);
        }
    }
    // ---- M-tile 1 (tokens tok0+16 .. tok0+31), acc1 ----
    __syncthreads();
    if (g > 0) {
        #pragma unroll
        for (int ct = 0; ct < NT; ct++)
            *(floatx4*)(&cb[((g - 1) * 64 + lane) * 28 + ct * 4]) = acc1[ct];
    }
    __syncthreads();
    if (g == 0) {
        #pragma unroll
        for (int o = 0; o < 3; o++)
            #pragma unroll
            for (int ct = 0; ct < NT; ct++)
                acc1[ct] += *(const floatx4*)(&cb[(o * 64 + lane) * 28 + ct * 4]);
        float z[4] = {0.f, 0.f, 0.f, 0.f};
        #pragma unroll
        for (int ct = 0; ct < NT; ct++) {
            float2 bw = *(const float2*)(b1w2 + (ct * 16 + u) * 2);
            #pragma unroll
            for (int r = 0; r < 4; r++)
                z[r] += tanhf(acc1[ct][r] + bw.x) * bw.y;
        }
        #pragma unroll
        for (int mask = 1; mask < 16; mask <<= 1) {
            #pragma unroll
            for (int r = 0; r < 4; r++) z[r] += __shfl_xor(z[r], mask, 64);
        }
        if (u == 0) {
            float bb2 = b2[0];
            #pragma unroll
            for (int r = 0; r < 4; r++)
                att[tok0 + 16 + q * 4 + r] = sigf(z[r] + bb2);
        }
    }
}

// ---------------------------------------------------------------------------
// K2: per batch row — word max via direct forward chase; one pass, one
// barrier. Reductions unchanged. (verified R1-R5)
// ---------------------------------------------------------------------------
__global__ __launch_bounds__(256) void k2_seg(
    const float* __restrict__ att, const int* __restrict__ offset,
    const float* __restrict__ labels, float* __restrict__ masked_out,
    float* __restrict__ sum_m, float* __restrict__ slab_o,
    float* __restrict__ tl_o, float* __restrict__ mino_o,
    float* __restrict__ maxm_o)
{
    const int b = blockIdx.x, tid = threadIdx.x;
    __shared__ float attl[Sn];
    __shared__ int   startl[Sn];
    __shared__ float rsum[4], rtl[4], rsl[4], rmn[4], rmx[4];

    for (int s = tid; s < Sn; s += 256) {
        attl[s] = att[b * Sn + s];
        startl[s] = (offset[(size_t)(b * Sn + s) * 2] == 0) ? 1 : 0;
    }
    __syncthreads();

    float lsum = 0.f, ltl = 0.f, lslab = -1e30f, lmin = 1e30f, lmax = -1e30f;
    for (int s = tid; s < Sn; s += 256) {
        float lab = labels[b * Sn + s];
        int st = startl[s];
        float m = 0.f;
        if (st && lab != -1.0f) {
            m = attl[s];
            for (int t = s + 1; t < Sn && !startl[t]; t++)
                m = fmaxf(m, attl[t]);
        }
        masked_out[b * Sn + s] = m;
        lsum += m;
        float zl = (lab == 1.0f) ? 1.f : 0.f;
        ltl += (m - zl) * (m - zl);
        lslab = fmaxf(lslab, lab);
        float om = (m == 0.f) ? 1.f : m;
        lmin = fminf(lmin, om);
        lmax = fmaxf(lmax, m);
    }
    int wid = tid >> 6, lane = tid & 63;
    lsum = wred_sum(lsum); ltl = wred_sum(ltl);
    lslab = wred_max(lslab); lmin = wred_min(lmin); lmax = wred_max(lmax);
    if (lane == 0) { rsum[wid]=lsum; rtl[wid]=ltl; rsl[wid]=lslab; rmn[wid]=lmin; rmx[wid]=lmax; }
    __syncthreads();
    if (tid == 0) {
        sum_m[b]  = rsum[0]+rsum[1]+rsum[2]+rsum[3];
        tl_o[b]   = rtl[0]+rtl[1]+rtl[2]+rtl[3];
        slab_o[b] = fmaxf(fmaxf(rsl[0],rsl[1]), fmaxf(rsl[2],rsl[3]));
        mino_o[b] = fminf(fminf(rmn[0],rmn[1]), fminf(rmn[2],rmn[3]));
        maxm_o[b] = fmaxf(fmaxf(rmx[0],rmx[1]), fmaxf(rmx[2],rmx[3]));
    }
}

// ---------------------------------------------------------------------------
// K3 (v3): pooled partials + FUSED h->out_hidden passthrough copy. The
// float4 just loaded for pooling is stored to out_hidden (fire-and-forget,
// no extra read pass). k3 is now a pure 200 MB stream (the m13 copy
// pattern) instead of k1 carrying the store on its critical path.
// grid (64 b, 16 sg) x 192 thr; block reduces 32 s-rows -> part[b][sg][768].
// ---------------------------------------------------------------------------
__global__ __launch_bounds__(192) void k3_pool(
    const float* __restrict__ h, const float* __restrict__ masked,
    const float* __restrict__ sum_m, float* __restrict__ part,
    float* __restrict__ out_hidden)
{
    const int b = blockIdx.x, sg = blockIdx.y;
    const int tid = threadIdx.x;
    __shared__ float nrm[32];
    if (tid < 32)
        nrm[tid] = masked[b * Sn + sg * 32 + tid] * (1.0f / sum_m[b]);
    __syncthreads();
    const size_t base = ((size_t)b * Sn + sg * 32) * Hn;
    const floatx4* hp = (const floatx4*)(h + base) + tid;
    float ax = 0.f, ay = 0.f, az = 0.f, aw = 0.f;
    #pragma unroll 8
    for (int s = 0; s < 32; s++) {
        floatx4 v = hp[(size_t)s * (Hn / 4)];
        *(floatx4*)(out_hidden + base + (size_t)s * Hn + tid * 4) = v;
        float w = nrm[s];
        ax += v.x * w; ay += v.y * w; az += v.z * w; aw += v.w * w;
    }
    floatx4 o; o.x = ax; o.y = ay; o.z = az; o.w = aw;
    *(floatx4*)(part + ((size_t)b * NSG + sg) * Hn + tid * 4) = o;
}

// ---------------------------------------------------------------------------
// K4: zpart[jc,b] = sum_{j in chunk} tanh(pooled[b]·W3T[j] + b3[j]) * W4[j].
// Prologue sums the 16 k3 partials into pl[].
// grid (64 b, 5 jc) x 256 threads; 4 threads per j, float4 dot over k.
// ---------------------------------------------------------------------------
__global__ __launch_bounds__(256) void k4_sent(
    const float* __restrict__ part, const float* __restrict__ w3t,
    const float* __restrict__ b3, const float* __restrict__ W4,
    float* __restrict__ zpart)
{
    const int b = blockIdx.x, jc = blockIdx.y;
    const int tid = threadIdx.x;
    __shared__ __align__(16) float pl[Hn];
    __shared__ float yred[64];
    for (int k = tid; k < Hn; k += 256) {
        float s = 0.f;
        #pragma unroll
        for (int g = 0; g < NSG; g++)
            s += part[((size_t)b * NSG + g) * Hn + k];
        pl[k] = s;
    }
    if (tid < 64) yred[tid] = 0.f;
    __syncthreads();
    int jj = tid >> 2, ks = tid & 3;
    float a = 0.f;
    if (jj < 60) {
        int j = jc * 60 + jj;
        const floatx4* wr = (const floatx4*)(w3t + (size_t)j * Hn) + ks * 48;
        const floatx4* pr = (const floatx4*)pl + ks * 48;
        #pragma unroll 8
        for (int i = 0; i < 48; i++) {
            floatx4 wv = wr[i]; floatx4 pv = pr[i];
            a += wv.x * pv.x + wv.y * pv.y + wv.z * pv.z + wv.w * pv.w;
        }
    }
    a += __shfl_xor(a, 1, 64);
    a += __shfl_xor(a, 2, 64);
    if (jj < 60 && ks == 0) {
        int j = jc * 60 + jj;
        yred[jj] = tanhf(a + b3[j]) * W4[j];
    }
    __syncthreads();
    if (tid < 64) {
        float y = yred[tid];
        y = wred_sum(y);
        if (tid == 0) zpart[jc * Bn + b] = y;
    }
}

// ---------------------------------------------------------------------------
// K5: sent + final scalars. One wave; b = lane.
// ---------------------------------------------------------------------------
__global__ __launch_bounds__(64) void k5_loss(
    const float* __restrict__ zpart, const float* __restrict__ b4,
    const float* __restrict__ slab, const float* __restrict__ tl,
    const float* __restrict__ mino, const float* __restrict__ maxm,
    float* __restrict__ out, float* __restrict__ out_sent)
{
    int t = threadIdx.x;
    float z = b4[0];
    #pragma unroll
    for (int jc = 0; jc < 5; jc++) z += zpart[jc * Bn + t];
    float sent = sigf(z);
    out_sent[t] = sent;
    float sl = slab[t];
    float e1 = (sent - sl) * (sent - sl);
    float e2 = tl[t];
    float e3 = mino[t] * mino[t];
    float mm = maxm[t] - sl;
    float e4 = mm * mm;
    e1 = wred_sum(e1); e2 = wred_sum(e2); e3 = wred_sum(e3); e4 = wred_sum(e4);
    if (t == 0) {
        out[1] = e1;
        out[2] = e2;
        out[3] = e3;
        out[4] = e4;
        out[0] = e1 + e2 + 0.01f * (e3 + e4);
    }
}

extern "C" void kernel_launch(void* const* d_in, const int* in_sizes, int n_in,
                              void* d_out, int out_size, void* d_ws, size_t ws_size,
                              hipStream_t stream) {
    (void)in_sizes; (void)n_in; (void)out_size; (void)ws_size;
    const float* h      = (const float*)d_in[0];
    const int*   offset = (const int*)d_in[1];
    const float* labels = (const float*)d_in[2];
    const float* W1     = (const float*)d_in[3];
    const float* b1     = (const float*)d_in[4];
    const float* W2     = (const float*)d_in[5];
    const float* b2     = (const float*)d_in[6];
    const float* W3     = (const float*)d_in[7];
    const float* b3     = (const float*)d_in[8];
    const float* W4     = (const float*)d_in[9];
    const float* b4     = (const float*)d_in[10];

    float* out        = (float*)d_out;
    float* out_hidden = out + 5;
    float* out_masked = out_hidden + (size_t)Bn * Sn * Hn;   // 25,165,824
    float* out_sent   = out_masked + (size_t)Bn * Sn;        // 32,768

    float* ws      = (float*)d_ws;
    float* att     = ws;                        // 32768
    float* sum_m   = att + Mtok;                // 64
    float* slab    = sum_m + Bn;
    float* tlb     = slab + Bn;
    float* mino    = tlb + Bn;
    float* maxm    = mino + Bn;
    float* part    = maxm + Bn;                 // 64*16*768 = 786432
    float* zpart   = part + (size_t)Bn * NSG * Hn;  // 320
    float* b1w2    = zpart + 5 * Bn;            // 224
    float* w3t     = b1w2 + 2 * NP;             // 230400
    unsigned short* w1t = (unsigned short*)(w3t + W3T_N);  // 86016 bf16

    int k0_total = W1T_N + Hn * ATT_H + W3T_N + NP;
    k0_prep<<<(k0_total + 255) / 256, 256, 0, stream>>>(W1, b1, W2, W3,
                                                        w1t, b1w2, w3t);
    k1_att<<<Mtok / 32, 256, 0, stream>>>(h, w1t, b1w2, b2, att);
    k2_seg<<<Bn, 256, 0, stream>>>(att, offset, labels, out_masked,
                                   sum_m, slab, tlb, mino, maxm);
    k3_pool<<<dim3(Bn, NSG), 192, 0, stream>>>(h, out_masked, sum_m, part,
                                               out_hidden);
    k4_sent<<<dim3(Bn, 5), 256, 0, stream>>>(part, w3t, b3, W4, zpart);
    k5_loss<<<1, 64, 0, stream>>>(zpart, b4, slab, tlb, mino, maxm, out, out_sent);
}

// Round 7
// 248.457 us; speedup vs baseline: 1.3790x; 1.0354x over previous
//
#include <hip/hip_runtime.h>
#include <math.h>

#define Bn 64
#define Sn 512
#define Hn 768
#define ATT_H 100
#define CLS_H 300
#define Mtok (Bn*Sn)          // 32768
#define NP 112                // padded ATT_H (7 x 16)
#define NT 7                  // col tiles of 16

#define W1T_N (NP*Hn)         // 86016 (fragment-ordered bf16)
#define W3T_N (CLS_H*Hn)      // 230400
#define NSG 16                // k3 s-groups (partials per batch row)
#define BCHUNK 14336          // B bytes per 64-k chunk (14 frags x 1024 B)

typedef __attribute__((ext_vector_type(8))) short short8;
typedef __attribute__((ext_vector_type(4))) float floatx4;

__device__ inline float sigf(float x) { return 1.0f / (1.0f + expf(-x)); }

__device__ inline unsigned short f2bf(float x) {
    union { float f; unsigned int u; } v; v.f = x;
    unsigned int r = (v.u + 0x7FFFu + ((v.u >> 16) & 1u)) >> 16;
    return (unsigned short)r;
}

__device__ inline float wred_sum(float v) {
    #pragma unroll
    for (int d = 32; d; d >>= 1) v += __shfl_down(v, d, 64);
    return v;
}
__device__ inline float wred_max(float v) {
    #pragma unroll
    for (int d = 32; d; d >>= 1) v = fmaxf(v, __shfl_down(v, d, 64));
    return v;
}
__device__ inline float wred_min(float v) {
    #pragma unroll
    for (int d = 32; d; d >>= 1) v = fminf(v, __shfl_down(v, d, 64));
    return v;
}

// ---------------------------------------------------------------------------
// K0: prep, coalesced reads + scatter writes.
// w1t FRAGMENT-ORDERED bf16: w1t[((kstep*7+ct)*64 + (q*16+u))*8 + e]
//   = W1[k][n], n = ct*16+u, k = kstep*32 + q*8 + e, zero-pad n >= ATT_H.
// w3t[j][k] = W3[k][j]; b1w2[n] = (b1[n], W2[n]).
// ---------------------------------------------------------------------------
__global__ __launch_bounds__(256) void k0_prep(
    const float* __restrict__ W1, const float* __restrict__ b1,
    const float* __restrict__ W2, const float* __restrict__ W3,
    unsigned short* __restrict__ w1t, float* __restrict__ b1w2,
    float* __restrict__ w3t)
{
    int idx = blockIdx.x * 256 + threadIdx.x;
    if (idx < W1T_N) {
        // zero-fill pad slots only (n >= ATT_H); real values written below
        int lane = (idx >> 3) & 63;
        int t = idx >> 9;                 // kstep*7 + ct
        int ct = t % 7;
        int n = ct * 16 + (lane & 15);
        if (n >= ATT_H) w1t[idx] = 0;
    } else if (idx < W1T_N + Hn * ATT_H) {
        int i = idx - W1T_N;              // i = k*ATT_H + n, coalesced read
        int k = i / ATT_H, n = i - k * ATT_H;
        int ct = n >> 4, u = n & 15;
        int kstep = k >> 5, q = (k & 31) >> 3, e = k & 7;
        w1t[((kstep * 7 + ct) * 64 + (q * 16 + u)) * 8 + e] = f2bf(W1[i]);
    } else if (idx < W1T_N + Hn * ATT_H + W3T_N) {
        int i = idx - (W1T_N + Hn * ATT_H);   // i = k*CLS_H + j, coalesced
        int k = i / CLS_H, j = i - k * CLS_H;
        w3t[(size_t)j * Hn + k] = W3[i];
    } else if (idx < W1T_N + Hn * ATT_H + W3T_N + NP) {
        int j = idx - (W1T_N + Hn * ATT_H + W3T_N);
        b1w2[2 * j]     = (j < ATT_H) ? b1[j] : 0.f;
        b1w2[2 * j + 1] = (j < ATT_H) ? W2[j] : 0.f;
    }
}

// ---------------------------------------------------------------------------
// K1 (v8): cooperative B-staging in LDS -- the DS-pipe bypass.
// R6 analysis: k1 at 47 us = (100 MB A-HBM + 172 MB B-L2)/5.8 TB/s, i.e. AT
// the vector-port ceiling; L1/L2 B hits still occupy the port. Fix: stage B
// in LDS once per block (all 4 waves share it), so B reads ride the DS pipe.
//  * block = 64 tokens = 4 waves x 16-row M-tiles; FULL k=768 per block
//    (12 chunks of 64 k) -> no k-split, no combine epilogue.
//  * per chunk: B 14 KB (bf16, fragment-ordered in w1t -> contiguous copy)
//    reg-staged by all 256 thr into dbuf LDS; A reg-prefetched (v[4]) and
//    packed to wave-private swizzled LDS (R5's measured-0-conflict layout).
//  * ONE barrier per chunk: stage B[ch+1] -> Bb[(ch+1)&1] right after the
//    barrier (its previous readers ran at ch-1, before that barrier);
//    compute ch reads Bb[ch&1] staged last iteration.
//  * B traffic 172 -> 86 MB and off the vm port; vm port carries A only.
//  * grid 512 = 2 blocks/CU (cross-block overlap covers barrier drains);
//    acc[7]+v[4]+breg[4] ~ 85 VGPR, launch_bounds(256,2) -> no spill.
// ---------------------------------------------------------------------------
__global__ __launch_bounds__(256, 2) void k1_att(
    const float* __restrict__ h, const unsigned short* __restrict__ w1t,
    const float* __restrict__ b1w2, const float* __restrict__ b2,
    float* __restrict__ att)
{
    __shared__ __align__(16) char Bb[2][BCHUNK];     // 28672 B
    __shared__ __align__(16) char Ab[4][2][2048];    // 16384 B

    const int tid = threadIdx.x;
    const int wave = tid >> 6, lane = tid & 63;
    const int u = lane & 15, q = lane >> 4;
    const int tokw = blockIdx.x * 64 + wave * 16;    // this wave's 16 tokens
    const int lr = lane >> 4;                        // 0..3 (row in quad)
    const int lcb = (lane & 15) * 8;                 // byte col (128-B rows)

    const char* __restrict__ w1b = (const char*)w1t;

    floatx4 acc[NT];
    #pragma unroll
    for (int ct = 0; ct < NT; ct++) acc[ct] = (floatx4)0.f;

    // ---- prologue ----
    floatx4 breg[4];
    #pragma unroll
    for (int p = 0; p < 4; p++) {                    // B[0] -> regs
        int off = tid * 16 + p * 4096;
        if (off < BCHUNK) breg[p] = *(const floatx4*)(w1b + off);
    }
    floatx4 v[4];
    #pragma unroll
    for (int j = 0; j < 4; j++)                      // A[0] -> regs
        v[j] = *(const floatx4*)(h + (size_t)(tokw + j * 4 + lr) * Hn
                                 + (lane & 15) * 4);
    #pragma unroll
    for (int p = 0; p < 4; p++) {                    // B[0] -> Bb[0]
        int off = tid * 16 + p * 4096;
        if (off < BCHUNK) *(floatx4*)(&Bb[0][off]) = breg[p];
    }
    #pragma unroll
    for (int p = 0; p < 4; p++) {                    // B[1] -> regs
        int off = tid * 16 + p * 4096;
        if (off < BCHUNK) breg[p] = *(const floatx4*)(w1b + BCHUNK + off);
    }

    // ---- main loop: 12 chunks of 64 k ----
    #pragma unroll 2
    for (int ch = 0; ch < 12; ch++) {
        __syncthreads();   // Bb[ch&1] visible; Bb[(ch+1)&1] readers (ch-1) done

        if (ch < 11) {     // stage B[ch+1]
            #pragma unroll
            for (int p = 0; p < 4; p++) {
                int off = tid * 16 + p * 4096;
                if (off < BCHUNK) *(floatx4*)(&Bb[(ch + 1) & 1][off]) = breg[p];
            }
        }
        if (ch < 10) {     // issue B[ch+2] loads (in flight through compute)
            #pragma unroll
            for (int p = 0; p < 4; p++) {
                int off = tid * 16 + p * 4096;
                if (off < BCHUNK)
                    breg[p] = *(const floatx4*)(w1b + (size_t)(ch + 2) * BCHUNK + off);
            }
        }

        // pack A[ch] -> wave-private swizzled LDS
        char* as = &Ab[wave][ch & 1][0];
        #pragma unroll
        for (int j = 0; j < 4; j++) {
            int row = j * 4 + lr;
            ushort4 bv;
            bv.x = f2bf(v[j].x); bv.y = f2bf(v[j].y);
            bv.z = f2bf(v[j].z); bv.w = f2bf(v[j].w);
            *(ushort4*)(as + row * 128 + (lcb ^ ((row & 7) << 4))) = bv;
        }
        // prefetch A[ch+1] (in flight through compute)
        if (ch < 11) {
            #pragma unroll
            for (int j = 0; j < 4; j++)
                v[j] = *(const floatx4*)(h + (size_t)(tokw + j * 4 + lr) * Hn
                                         + (ch + 1) * 64 + (lane & 15) * 4);
        }

        // compute chunk ch: 2 k-steps x 7 ct
        const char* bs = &Bb[ch & 1][0];
        #pragma unroll
        for (int ks = 0; ks < 2; ks++) {
            short8 a = *(const short8*)(as + u * 128
                                        + ((ks * 64 + q * 16) ^ ((u & 7) << 4)));
            #pragma unroll
            for (int ct = 0; ct < NT; ct++) {
                short8 bfr = *(const short8*)(bs + ((ks * 7 + ct) * 64 + lane) * 16);
                acc[ct] = __builtin_amdgcn_mfma_f32_16x16x32_bf16(a, bfr, acc[ct], 0, 0, 0);
            }
        }
    }

    // ---- epilogue (full k in acc; no combine) ----
    float z[4] = {0.f, 0.f, 0.f, 0.f};
    #pragma unroll
    for (int ct = 0; ct < NT; ct++) {
        float2 bw = *(const float2*)(b1w2 + (ct * 16 + u) * 2);
        #pragma unroll
        for (int r = 0; r < 4; r++)
            z[r] += tanhf(acc[ct][r] + bw.x) * bw.y;
    }
    #pragma unroll
    for (int mask = 1; mask < 16; mask <<= 1) {
        #pragma unroll
        for (int r = 0; r < 4; r++) z[r] += __shfl_xor(z[r], mask, 64);
    }
    if (u == 0) {
        float bb2 = b2[0];
        #pragma unroll
        for (int r = 0; r < 4; r++)
            att[tokw + q * 4 + r] = sigf(z[r] + bb2);
    }
}

// ---------------------------------------------------------------------------
// K3 (v4): k2 FOLDED IN. Each (b,sg) block recomputes the row scan (word-max
// chase + masks + reductions; LDS-local, 16x redundant but tiny) so the k2
// kernel/launch disappears; the sg==0 block writes masked_out + scalars.
// Reduction loops keep k2's exact 256-thread stride -> identical FP order.
// Then: pooling partials for rows sg*32..+32 + fused h->out_hidden copy.
// grid (64 b, 16 sg) x 256 thr.
// ---------------------------------------------------------------------------
__global__ __launch_bounds__(256) void k3_pool(
    const float* __restrict__ h, const float* __restrict__ att,
    const int* __restrict__ offset, const float* __restrict__ labels,
    float* __restrict__ masked_out, float* __restrict__ part,
    float* __restrict__ out_hidden,
    float* __restrict__ slab_o, float* __restrict__ tl_o,
    float* __restrict__ mino_o, float* __restrict__ maxm_o)
{
    const int b = blockIdx.x, sg = blockIdx.y, tid = threadIdx.x;
    __shared__ float attl[Sn];
    __shared__ int   startl[Sn];
    __shared__ float ml[Sn];
    __shared__ float rsum[4], rtl[4], rsl[4], rmn[4], rmx[4];

    for (int s = tid; s < Sn; s += 256) {
        attl[s] = att[b * Sn + s];
        startl[s] = (offset[(size_t)(b * Sn + s) * 2] == 0) ? 1 : 0;
    }
    __syncthreads();

    float lsum = 0.f, ltl = 0.f, lslab = -1e30f, lmin = 1e30f, lmax = -1e30f;
    for (int s = tid; s < Sn; s += 256) {
        float lab = labels[b * Sn + s];
        int st = startl[s];
        float m = 0.f;
        if (st && lab != -1.0f) {
            m = attl[s];
            for (int t2 = s + 1; t2 < Sn && !startl[t2]; t2++)
                m = fmaxf(m, attl[t2]);
        }
        ml[s] = m;
        lsum += m;
        float zl = (lab == 1.0f) ? 1.f : 0.f;
        ltl += (m - zl) * (m - zl);
        lslab = fmaxf(lslab, lab);
        float om = (m == 0.f) ? 1.f : m;
        lmin = fminf(lmin, om);
        lmax = fmaxf(lmax, m);
    }
    int wid = tid >> 6, lane = tid & 63;
    lsum = wred_sum(lsum); ltl = wred_sum(ltl);
    lslab = wred_max(lslab); lmin = wred_min(lmin); lmax = wred_max(lmax);
    if (lane == 0) { rsum[wid]=lsum; rtl[wid]=ltl; rsl[wid]=lslab; rmn[wid]=lmin; rmx[wid]=lmax; }
    __syncthreads();   // rsum + ml visible

    if (sg == 0) {
        if (tid == 0) {
            tl_o[b]   = rtl[0]+rtl[1]+rtl[2]+rtl[3];
            slab_o[b] = fmaxf(fmaxf(rsl[0],rsl[1]), fmaxf(rsl[2],rsl[3]));
            mino_o[b] = fminf(fminf(rmn[0],rmn[1]), fminf(rmn[2],rmn[3]));
            maxm_o[b] = fmaxf(fmaxf(rmx[0],rmx[1]), fmaxf(rmx[2],rmx[3]));
        }
        for (int s = tid; s < Sn; s += 256) masked_out[b * Sn + s] = ml[s];
    }

    float inv = 1.0f / (rsum[0]+rsum[1]+rsum[2]+rsum[3]);
    if (tid < 192) {
        const size_t base = ((size_t)b * Sn + sg * 32) * Hn;
        const floatx4* hp = (const floatx4*)(h + base) + tid;
        float ax = 0.f, ay = 0.f, az = 0.f, aw = 0.f;
        #pragma unroll 8
        for (int s = 0; s < 32; s++) {
            floatx4 vv = hp[(size_t)s * (Hn / 4)];
            *(floatx4*)(out_hidden + base + (size_t)s * Hn + tid * 4) = vv;
            float w = ml[sg * 32 + s] * inv;
            ax += vv.x * w; ay += vv.y * w; az += vv.z * w; aw += vv.w * w;
        }
        floatx4 o; o.x = ax; o.y = ay; o.z = az; o.w = aw;
        *(floatx4*)(part + ((size_t)b * NSG + sg) * Hn + tid * 4) = o;
    }
}

// ---------------------------------------------------------------------------
// K4: zpart[jc,b] = sum_{j in chunk} tanh(pooled[b]·W3T[j] + b3[j]) * W4[j].
// Prologue sums the 16 k3 partials into pl[].
// grid (64 b, 5 jc) x 256 threads; 4 threads per j, float4 dot over k.
// ---------------------------------------------------------------------------
__global__ __launch_bounds__(256) void k4_sent(
    const float* __restrict__ part, const float* __restrict__ w3t,
    const float* __restrict__ b3, const float* __restrict__ W4,
    float* __restrict__ zpart)
{
    const int b = blockIdx.x, jc = blockIdx.y;
    const int tid = threadIdx.x;
    __shared__ __align__(16) float pl[Hn];
    __shared__ float yred[64];
    for (int k = tid; k < Hn; k += 256) {
        float s = 0.f;
        #pragma unroll
        for (int g = 0; g < NSG; g++)
            s += part[((size_t)b * NSG + g) * Hn + k];
        pl[k] = s;
    }
    if (tid < 64) yred[tid] = 0.f;
    __syncthreads();
    int jj = tid >> 2, ks = tid & 3;
    float a = 0.f;
    if (jj < 60) {
        int j = jc * 60 + jj;
        const floatx4* wr = (const floatx4*)(w3t + (size_t)j * Hn) + ks * 48;
        const floatx4* pr = (const floatx4*)pl + ks * 48;
        #pragma unroll 8
        for (int i = 0; i < 48; i++) {
            floatx4 wv = wr[i]; floatx4 pv = pr[i];
            a += wv.x * pv.x + wv.y * pv.y + wv.z * pv.z + wv.w * pv.w;
        }
    }
    a += __shfl_xor(a, 1, 64);
    a += __shfl_xor(a, 2, 64);
    if (jj < 60 && ks == 0) {
        int j = jc * 60 + jj;
        yred[jj] = tanhf(a + b3[j]) * W4[j];
    }
    __syncthreads();
    if (tid < 64) {
        float y = yred[tid];
        y = wred_sum(y);
        if (tid == 0) zpart[jc * Bn + b] = y;
    }
}

// ---------------------------------------------------------------------------
// K5: sent + final scalars. One wave; b = lane.
// ---------------------------------------------------------------------------
__global__ __launch_bounds__(64) void k5_loss(
    const float* __restrict__ zpart, const float* __restrict__ b4,
    const float* __restrict__ slab, const float* __restrict__ tl,
    const float* __restrict__ mino, const float* __restrict__ maxm,
    float* __restrict__ out, float* __restrict__ out_sent)
{
    int t = threadIdx.x;
    float z = b4[0];
    #pragma unroll
    for (int jc = 0; jc < 5; jc++) z += zpart[jc * Bn + t];
    float sent = sigf(z);
    out_sent[t] = sent;
    float sl = slab[t];
    float e1 = (sent - sl) * (sent - sl);
    float e2 = tl[t];
    float e3 = mino[t] * mino[t];
    float mm = maxm[t] - sl;
    float e4 = mm * mm;
    e1 = wred_sum(e1); e2 = wred_sum(e2); e3 = wred_sum(e3); e4 = wred_sum(e4);
    if (t == 0) {
        out[1] = e1;
        out[2] = e2;
        out[3] = e3;
        out[4] = e4;
        out[0] = e1 + e2 + 0.01f * (e3 + e4);
    }
}

extern "C" void kernel_launch(void* const* d_in, const int* in_sizes, int n_in,
                              void* d_out, int out_size, void* d_ws, size_t ws_size,
                              hipStream_t stream) {
    (void)in_sizes; (void)n_in; (void)out_size; (void)ws_size;
    const float* h      = (const float*)d_in[0];
    const int*   offset = (const int*)d_in[1];
    const float* labels = (const float*)d_in[2];
    const float* W1     = (const float*)d_in[3];
    const float* b1     = (const float*)d_in[4];
    const float* W2     = (const float*)d_in[5];
    const float* b2     = (const float*)d_in[6];
    const float* W3     = (const float*)d_in[7];
    const float* b3     = (const float*)d_in[8];
    const float* W4     = (const float*)d_in[9];
    const float* b4     = (const float*)d_in[10];

    float* out        = (float*)d_out;
    float* out_hidden = out + 5;
    float* out_masked = out_hidden + (size_t)Bn * Sn * Hn;   // 25,165,824
    float* out_sent   = out_masked + (size_t)Bn * Sn;        // 32,768

    float* ws      = (float*)d_ws;
    float* att     = ws;                        // 32768
    float* sum_m   = att + Mtok;                // 64 (unused, layout keeper)
    float* slab    = sum_m + Bn;
    float* tlb     = slab + Bn;
    float* mino    = tlb + Bn;
    float* maxm    = mino + Bn;
    float* part    = maxm + Bn;                 // 64*16*768 = 786432
    float* zpart   = part + (size_t)Bn * NSG * Hn;  // 320
    float* b1w2    = zpart + 5 * Bn;            // 224
    float* w3t     = b1w2 + 2 * NP;             // 230400
    unsigned short* w1t = (unsigned short*)(w3t + W3T_N);  // 86016 bf16

    int k0_total = W1T_N + Hn * ATT_H + W3T_N + NP;
    k0_prep<<<(k0_total + 255) / 256, 256, 0, stream>>>(W1, b1, W2, W3,
                                                        w1t, b1w2, w3t);
    k1_att<<<Mtok / 64, 256, 0, stream>>>(h, w1t, b1w2, b2, att);
    k3_pool<<<dim3(Bn, NSG), 256, 0, stream>>>(h, att, offset, labels,
                                               out_masked, part, out_hidden,
                                               slab, tlb, mino, maxm);
    k4_sent<<<dim3(Bn, 5), 256, 0, stream>>>(part, w3t, b3, W4, zpart);
    k5_loss<<<1, 64, 0, stream>>>(zpart, b4, slab, tlb, mino, maxm, out, out_sent);
}

// Round 8
// 248.396 us; speedup vs baseline: 1.3793x; 1.0002x over previous
//
#include <hip/hip_runtime.h>
#include <math.h>

#define Bn 64
#define Sn 512
#define Hn 768
#define ATT_H 100
#define CLS_H 300
#define Mtok (Bn*Sn)          // 32768
#define NP 112                // padded ATT_H (7 x 16)
#define NT 7                  // col tiles of 16

#define W1T_N (NP*Hn)         // 86016 (fragment-ordered bf16)
#define W3T_N (CLS_H*Hn)      // 230400
#define NSG 16                // k3 s-groups (partials per batch row)
#define BCHUNK 14336          // B bytes per 64-k chunk (14 frags x 1024 B)

typedef __attribute__((ext_vector_type(8))) short short8;
typedef __attribute__((ext_vector_type(4))) float floatx4;

__device__ inline float sigf(float x) { return 1.0f / (1.0f + expf(-x)); }

__device__ inline unsigned short f2bf(float x) {
    union { float f; unsigned int u; } v; v.f = x;
    unsigned int r = (v.u + 0x7FFFu + ((v.u >> 16) & 1u)) >> 16;
    return (unsigned short)r;
}

__device__ inline float wred_sum(float v) {
    #pragma unroll
    for (int d = 32; d; d >>= 1) v += __shfl_down(v, d, 64);
    return v;
}
__device__ inline float wred_max(float v) {
    #pragma unroll
    for (int d = 32; d; d >>= 1) v = fmaxf(v, __shfl_down(v, d, 64));
    return v;
}
__device__ inline float wred_min(float v) {
    #pragma unroll
    for (int d = 32; d; d >>= 1) v = fminf(v, __shfl_down(v, d, 64));
    return v;
}

// ---------------------------------------------------------------------------
// K0: prep, coalesced reads + scatter writes.
// w1t FRAGMENT-ORDERED bf16: w1t[((kstep*7+ct)*64 + (q*16+u))*8 + e]
//   = W1[k][n], n = ct*16+u, k = kstep*32 + q*8 + e, zero-pad n >= ATT_H.
// w3t[j][k] = W3[k][j]; b1w2[n] = (b1[n], W2[n]).
// ---------------------------------------------------------------------------
__global__ __launch_bounds__(256) void k0_prep(
    const float* __restrict__ W1, const float* __restrict__ b1,
    const float* __restrict__ W2, const float* __restrict__ W3,
    unsigned short* __restrict__ w1t, float* __restrict__ b1w2,
    float* __restrict__ w3t)
{
    int idx = blockIdx.x * 256 + threadIdx.x;
    if (idx < W1T_N) {
        // zero-fill pad slots only (n >= ATT_H); real values written below
        int lane = (idx >> 3) & 63;
        int t = idx >> 9;                 // kstep*7 + ct
        int ct = t % 7;
        int n = ct * 16 + (lane & 15);
        if (n >= ATT_H) w1t[idx] = 0;
    } else if (idx < W1T_N + Hn * ATT_H) {
        int i = idx - W1T_N;              // i = k*ATT_H + n, coalesced read
        int k = i / ATT_H, n = i - k * ATT_H;
        int ct = n >> 4, u = n & 15;
        int kstep = k >> 5, q = (k & 31) >> 3, e = k & 7;
        w1t[((kstep * 7 + ct) * 64 + (q * 16 + u)) * 8 + e] = f2bf(W1[i]);
    } else if (idx < W1T_N + Hn * ATT_H + W3T_N) {
        int i = idx - (W1T_N + Hn * ATT_H);   // i = k*CLS_H + j, coalesced
        int k = i / CLS_H, j = i - k * CLS_H;
        w3t[(size_t)j * Hn + k] = W3[i];
    } else if (idx < W1T_N + Hn * ATT_H + W3T_N + NP) {
        int j = idx - (W1T_N + Hn * ATT_H + W3T_N);
        b1w2[2 * j]     = (j < ATT_H) ? b1[j] : 0.f;
        b1w2[2 * j + 1] = (j < ATT_H) ? W2[j] : 0.f;
    }
}

// ---------------------------------------------------------------------------
// K1 (v9): v8 structure, doubled token-block to halve B traffic.
// R7 port accounting (v8): per CU = 2 blk x 12 ch x (A 16 KB + B 14 KB)
// = 720 KB @ ~10 B/cyc/CU = 30 us. B is half the port traffic because each
// 64-token block re-reads all 168 KB of w1t. v9: block = 128 tokens
// (8 waves x 16-token M-tiles, 512 thr), grid 256 -> per CU 12 x (A 32 KB +
// B 14 KB) = 552 KB = ~23 us. One barrier per chunk (same proven schedule);
// 1 block/CU is fine because chunk time is port-service-bound (4.6 K cyc >>
// 900-cyc load latency) so the barrier drain is covered by the port queue.
// LDS 28.7 KB Bb + 32 KB Ab = 61.4 KB; regs ~80 (acc 28 + v 16 + breg 8),
// __launch_bounds__(512,2) -> cap 256, no spill. A-pack uses R5's
// measured-0-conflict swizzle (128 B rows, byte^=(row&7)<<4).
// ---------------------------------------------------------------------------
__global__ __launch_bounds__(512, 2) void k1_att(
    const float* __restrict__ h, const unsigned short* __restrict__ w1t,
    const float* __restrict__ b1w2, const float* __restrict__ b2,
    float* __restrict__ att)
{
    __shared__ __align__(16) char Bb[2][BCHUNK];     // 28672 B
    __shared__ __align__(16) char Ab[8][2][2048];    // 32768 B

    const int tid = threadIdx.x;
    const int wave = tid >> 6, lane = tid & 63;
    const int u = lane & 15, q = lane >> 4;
    const int tokw = blockIdx.x * 128 + wave * 16;   // this wave's 16 tokens
    const int lr = lane >> 4;                        // 0..3 (row in quad)
    const int lcb = (lane & 15) * 8;                 // byte col (128-B rows)

    const char* __restrict__ w1b = (const char*)w1t;

    floatx4 acc[NT];
    #pragma unroll
    for (int ct = 0; ct < NT; ct++) acc[ct] = (floatx4)0.f;

    // ---- prologue ----
    floatx4 breg[2];
    #pragma unroll
    for (int p = 0; p < 2; p++) {                    // B[0] -> regs
        int off = tid * 16 + p * 8192;
        if (off < BCHUNK) breg[p] = *(const floatx4*)(w1b + off);
    }
    floatx4 v[4];
    #pragma unroll
    for (int j = 0; j < 4; j++)                      // A[0] -> regs
        v[j] = *(const floatx4*)(h + (size_t)(tokw + j * 4 + lr) * Hn
                                 + (lane & 15) * 4);
    #pragma unroll
    for (int p = 0; p < 2; p++) {                    // B[0] -> Bb[0]
        int off = tid * 16 + p * 8192;
        if (off < BCHUNK) *(floatx4*)(&Bb[0][off]) = breg[p];
    }
    #pragma unroll
    for (int p = 0; p < 2; p++) {                    // B[1] -> regs
        int off = tid * 16 + p * 8192;
        if (off < BCHUNK) breg[p] = *(const floatx4*)(w1b + BCHUNK + off);
    }

    // ---- main loop: 12 chunks of 64 k ----
    #pragma unroll 2
    for (int ch = 0; ch < 12; ch++) {
        __syncthreads();   // Bb[ch&1] visible; Bb[(ch+1)&1] readers (ch-1) done

        if (ch < 11) {     // stage B[ch+1]
            #pragma unroll
            for (int p = 0; p < 2; p++) {
                int off = tid * 16 + p * 8192;
                if (off < BCHUNK) *(floatx4*)(&Bb[(ch + 1) & 1][off]) = breg[p];
            }
        }
        if (ch < 10) {     // issue B[ch+2] loads (in flight through compute)
            #pragma unroll
            for (int p = 0; p < 2; p++) {
                int off = tid * 16 + p * 8192;
                if (off < BCHUNK)
                    breg[p] = *(const floatx4*)(w1b + (size_t)(ch + 2) * BCHUNK + off);
            }
        }

        // pack A[ch] -> wave-private swizzled LDS
        char* as = &Ab[wave][ch & 1][0];
        #pragma unroll
        for (int j = 0; j < 4; j++) {
            int row = j * 4 + lr;
            ushort4 bv;
            bv.x = f2bf(v[j].x); bv.y = f2bf(v[j].y);
            bv.z = f2bf(v[j].z); bv.w = f2bf(v[j].w);
            *(ushort4*)(as + row * 128 + (lcb ^ ((row & 7) << 4))) = bv;
        }
        // prefetch A[ch+1] (in flight through compute)
        if (ch < 11) {
            #pragma unroll
            for (int j = 0; j < 4; j++)
                v[j] = *(const floatx4*)(h + (size_t)(tokw + j * 4 + lr) * Hn
                                         + (ch + 1) * 64 + (lane & 15) * 4);
        }

        // compute chunk ch: 2 k-steps x 7 ct
        const char* bs = &Bb[ch & 1][0];
        #pragma unroll
        for (int ks = 0; ks < 2; ks++) {
            short8 a = *(const short8*)(as + u * 128
                                        + ((ks * 64 + q * 16) ^ ((u & 7) << 4)));
            #pragma unroll
            for (int ct = 0; ct < NT; ct++) {
                short8 bfr = *(const short8*)(bs + ((ks * 7 + ct) * 64 + lane) * 16);
                acc[ct] = __builtin_amdgcn_mfma_f32_16x16x32_bf16(a, bfr, acc[ct], 0, 0, 0);
            }
        }
    }

    // ---- epilogue (full k in acc; no combine) ----
    float z[4] = {0.f, 0.f, 0.f, 0.f};
    #pragma unroll
    for (int ct = 0; ct < NT; ct++) {
        float2 bw = *(const float2*)(b1w2 + (ct * 16 + u) * 2);
        #pragma unroll
        for (int r = 0; r < 4; r++)
            z[r] += tanhf(acc[ct][r] + bw.x) * bw.y;
    }
    #pragma unroll
    for (int mask = 1; mask < 16; mask <<= 1) {
        #pragma unroll
        for (int r = 0; r < 4; r++) z[r] += __shfl_xor(z[r], mask, 64);
    }
    if (u == 0) {
        float bb2 = b2[0];
        #pragma unroll
        for (int r = 0; r < 4; r++)
            att[tokw + q * 4 + r] = sigf(z[r] + bb2);
    }
}

// ---------------------------------------------------------------------------
// K3 (v4): k2 folded in. Each (b,sg) block recomputes the row scan (word-max
// chase + masks + reductions; LDS-local, 16x redundant but tiny); the sg==0
// block writes masked_out + scalars. Reduction loops keep k2's exact
// 256-thread stride -> identical FP order. Then: pooling partials for rows
// sg*32..+32 + fused h->out_hidden copy. grid (64 b, 16 sg) x 256 thr.
// ---------------------------------------------------------------------------
__global__ __launch_bounds__(256) void k3_pool(
    const float* __restrict__ h, const float* __restrict__ att,
    const int* __restrict__ offset, const float* __restrict__ labels,
    float* __restrict__ masked_out, float* __restrict__ part,
    float* __restrict__ out_hidden,
    float* __restrict__ slab_o, float* __restrict__ tl_o,
    float* __restrict__ mino_o, float* __restrict__ maxm_o)
{
    const int b = blockIdx.x, sg = blockIdx.y, tid = threadIdx.x;
    __shared__ float attl[Sn];
    __shared__ int   startl[Sn];
    __shared__ float ml[Sn];
    __shared__ float rsum[4], rtl[4], rsl[4], rmn[4], rmx[4];

    for (int s = tid; s < Sn; s += 256) {
        attl[s] = att[b * Sn + s];
        startl[s] = (offset[(size_t)(b * Sn + s) * 2] == 0) ? 1 : 0;
    }
    __syncthreads();

    float lsum = 0.f, ltl = 0.f, lslab = -1e30f, lmin = 1e30f, lmax = -1e30f;
    for (int s = tid; s < Sn; s += 256) {
        float lab = labels[b * Sn + s];
        int st = startl[s];
        float m = 0.f;
        if (st && lab != -1.0f) {
            m = attl[s];
            for (int t2 = s + 1; t2 < Sn && !startl[t2]; t2++)
                m = fmaxf(m, attl[t2]);
        }
        ml[s] = m;
        lsum += m;
        float zl = (lab == 1.0f) ? 1.f : 0.f;
        ltl += (m - zl) * (m - zl);
        lslab = fmaxf(lslab, lab);
        float om = (m == 0.f) ? 1.f : m;
        lmin = fminf(lmin, om);
        lmax = fmaxf(lmax, m);
    }
    int wid = tid >> 6, lane = tid & 63;
    lsum = wred_sum(lsum); ltl = wred_sum(ltl);
    lslab = wred_max(lslab); lmin = wred_min(lmin); lmax = wred_max(lmax);
    if (lane == 0) { rsum[wid]=lsum; rtl[wid]=ltl; rsl[wid]=lslab; rmn[wid]=lmin; rmx[wid]=lmax; }
    __syncthreads();   // rsum + ml visible

    if (sg == 0) {
        if (tid == 0) {
            tl_o[b]   = rtl[0]+rtl[1]+rtl[2]+rtl[3];
            slab_o[b] = fmaxf(fmaxf(rsl[0],rsl[1]), fmaxf(rsl[2],rsl[3]));
            mino_o[b] = fminf(fminf(rmn[0],rmn[1]), fminf(rmn[2],rmn[3]));
            maxm_o[b] = fmaxf(fmaxf(rmx[0],rmx[1]), fmaxf(rmx[2],rmx[3]));
        }
        for (int s = tid; s < Sn; s += 256) masked_out[b * Sn + s] = ml[s];
    }

    float inv = 1.0f / (rsum[0]+rsum[1]+rsum[2]+rsum[3]);
    if (tid < 192) {
        const size_t base = ((size_t)b * Sn + sg * 32) * Hn;
        const floatx4* hp = (const floatx4*)(h + base) + tid;
        float ax = 0.f, ay = 0.f, az = 0.f, aw = 0.f;
        #pragma unroll 8
        for (int s = 0; s < 32; s++) {
            floatx4 vv = hp[(size_t)s * (Hn / 4)];
            *(floatx4*)(out_hidden + base + (size_t)s * Hn + tid * 4) = vv;
            float w = ml[sg * 32 + s] * inv;
            ax += vv.x * w; ay += vv.y * w; az += vv.z * w; aw += vv.w * w;
        }
        floatx4 o; o.x = ax; o.y = ay; o.z = az; o.w = aw;
        *(floatx4*)(part + ((size_t)b * NSG + sg) * Hn + tid * 4) = o;
    }
}

// ---------------------------------------------------------------------------
// K4: zpart[jc,b] = sum_{j in chunk} tanh(pooled[b]·W3T[j] + b3[j]) * W4[j].
// Prologue sums the 16 k3 partials into pl[].
// grid (64 b, 5 jc) x 256 threads; 4 threads per j, float4 dot over k.
// ---------------------------------------------------------------------------
__global__ __launch_bounds__(256) void k4_sent(
    const float* __restrict__ part, const float* __restrict__ w3t,
    const float* __restrict__ b3, const float* __restrict__ W4,
    float* __restrict__ zpart)
{
    const int b = blockIdx.x, jc = blockIdx.y;
    const int tid = threadIdx.x;
    __shared__ __align__(16) float pl[Hn];
    __shared__ float yred[64];
    for (int k = tid; k < Hn; k += 256) {
        float s = 0.f;
        #pragma unroll
        for (int g = 0; g < NSG; g++)
            s += part[((size_t)b * NSG + g) * Hn + k];
        pl[k] = s;
    }
    if (tid < 64) yred[tid] = 0.f;
    __syncthreads();
    int jj = tid >> 2, ks = tid & 3;
    float a = 0.f;
    if (jj < 60) {
        int j = jc * 60 + jj;
        const floatx4* wr = (const floatx4*)(w3t + (size_t)j * Hn) + ks * 48;
        const floatx4* pr = (const floatx4*)pl + ks * 48;
        #pragma unroll 8
        for (int i = 0; i < 48; i++) {
            floatx4 wv = wr[i]; floatx4 pv = pr[i];
            a += wv.x * pv.x + wv.y * pv.y + wv.z * pv.z + wv.w * pv.w;
        }
    }
    a += __shfl_xor(a, 1, 64);
    a += __shfl_xor(a, 2, 64);
    if (jj < 60 && ks == 0) {
        int j = jc * 60 + jj;
        yred[jj] = tanhf(a + b3[j]) * W4[j];
    }
    __syncthreads();
    if (tid < 64) {
        float y = yred[tid];
        y = wred_sum(y);
        if (tid == 0) zpart[jc * Bn + b] = y;
    }
}

// ---------------------------------------------------------------------------
// K5: sent + final scalars. One wave; b = lane.
// ---------------------------------------------------------------------------
__global__ __launch_bounds__(64) void k5_loss(
    const float* __restrict__ zpart, const float* __restrict__ b4,
    const float* __restrict__ slab, const float* __restrict__ tl,
    const float* __restrict__ mino, const float* __restrict__ maxm,
    float* __restrict__ out, float* __restrict__ out_sent)
{
    int t = threadIdx.x;
    float z = b4[0];
    #pragma unroll
    for (int jc = 0; jc < 5; jc++) z += zpart[jc * Bn + t];
    float sent = sigf(z);
    out_sent[t] = sent;
    float sl = slab[t];
    float e1 = (sent - sl) * (sent - sl);
    float e2 = tl[t];
    float e3 = mino[t] * mino[t];
    float mm = maxm[t] - sl;
    float e4 = mm * mm;
    e1 = wred_sum(e1); e2 = wred_sum(e2); e3 = wred_sum(e3); e4 = wred_sum(e4);
    if (t == 0) {
        out[1] = e1;
        out[2] = e2;
        out[3] = e3;
        out[4] = e4;
        out[0] = e1 + e2 + 0.01f * (e3 + e4);
    }
}

extern "C" void kernel_launch(void* const* d_in, const int* in_sizes, int n_in,
                              void* d_out, int out_size, void* d_ws, size_t ws_size,
                              hipStream_t stream) {
    (void)in_sizes; (void)n_in; (void)out_size; (void)ws_size;
    const float* h      = (const float*)d_in[0];
    const int*   offset = (const int*)d_in[1];
    const float* labels = (const float*)d_in[2];
    const float* W1     = (const float*)d_in[3];
    const float* b1     = (const float*)d_in[4];
    const float* W2     = (const float*)d_in[5];
    const float* b2     = (const float*)d_in[6];
    const float* W3     = (const float*)d_in[7];
    const float* b3     = (const float*)d_in[8];
    const float* W4     = (const float*)d_in[9];
    const float* b4     = (const float*)d_in[10];

    float* out        = (float*)d_out;
    float* out_hidden = out + 5;
    float* out_masked = out_hidden + (size_t)Bn * Sn * Hn;   // 25,165,824
    float* out_sent   = out_masked + (size_t)Bn * Sn;        // 32,768

    float* ws      = (float*)d_ws;
    float* att     = ws;                        // 32768
    float* sum_m   = att + Mtok;                // 64 (unused, layout keeper)
    float* slab    = sum_m + Bn;
    float* tlb     = slab + Bn;
    float* mino    = tlb + Bn;
    float* maxm    = mino + Bn;
    float* part    = maxm + Bn;                 // 64*16*768 = 786432
    float* zpart   = part + (size_t)Bn * NSG * Hn;  // 320
    float* b1w2    = zpart + 5 * Bn;            // 224
    float* w3t     = b1w2 + 2 * NP;             // 230400
    unsigned short* w1t = (unsigned short*)(w3t + W3T_N);  // 86016 bf16

    int k0_total = W1T_N + Hn * ATT_H + W3T_N + NP;
    k0_prep<<<(k0_total + 255) / 256, 256, 0, stream>>>(W1, b1, W2, W3,
                                                        w1t, b1w2, w3t);
    k1_att<<<Mtok / 128, 512, 0, stream>>>(h, w1t, b1w2, b2, att);
    k3_pool<<<dim3(Bn, NSG), 256, 0, stream>>>(h, att, offset, labels,
                                               out_masked, part, out_hidden,
                                               slab, tlb, mino, maxm);
    k4_sent<<<dim3(Bn, 5), 256, 0, stream>>>(part, w3t, b3, W4, zpart);
    k5_loss<<<1, 64, 0, stream>>>(zpart, b4, slab, tlb, mino, maxm, out, out_sent);
}